// Round 2
// baseline (874.077 us; speedup 1.0000x reference)
//
#include <hip/hip_runtime.h>
#include <hip/hip_bf16.h>
#include <math.h>

typedef unsigned short u16;
typedef unsigned int   u32;
typedef __attribute__((ext_vector_type(8))) short s16x8;
typedef __attribute__((ext_vector_type(4))) float f32x4;

#define CB 768
#define NB 256
#define FB 512
#define BATCH 1024
#define OUTC 131073
#define LOGF 6.2383246250395077f

// master (fp32 canonical) element offsets, setup_inputs order
#define OFF_X    0
#define OFF_GIN  786432
#define OFF_BIN  787200
#define OFF_CW1  787968
#define OFF_CB1  1377792
#define OFF_CW2  1378560
#define OFF_CB2  1968384
#define OFF_CW3  1969152
#define OFF_CB3  2165760
#define OFF_EMB  2166016
#define OFF_GE   2362624
#define OFF_BE   2363392
#define OFF_FW1  2364160
#define OFF_FB1  3543808
#define OFF_FW2  3544576
#define OFF_FB2  4134400
#define OFF_FW3  4135168
#define OFF_FB3  4528384
#define OFF_NW   4528896
#define OFF_NB   4529664
#define MASTER_TOTAL 4529665

struct Ptrs20 { const void* p[20]; };

__device__ __forceinline__ u16 f2bf(float f){
    u32 u = __float_as_uint(f);
    u32 r = u + 0x7FFFu + ((u >> 16) & 1u);
    return (u16)(r >> 16);
}
__device__ __forceinline__ float bf2f(u16 s){ return __uint_as_float(((u32)s) << 16); }

__device__ __forceinline__ float gelu_f(float x){
    return 0.5f * x * (1.0f + tanhf(0.7978845608028654f * (x + 0.044715f * x * x * x)));
}

__device__ __forceinline__ f32x4 mfma16x16x32(s16x8 a, s16x8 b, f32x4 c){
    return __builtin_amdgcn_mfma_f32_16x16x32_bf16(a, b, c, 0, 0, 0);
}

__device__ __forceinline__ float blockReduce(float v, float* sb, bool domax){
    #pragma unroll
    for (int o = 32; o > 0; o >>= 1){
        float ov = __shfl_down(v, o, 64);
        v = domax ? fmaxf(v, ov) : (v + ov);
    }
    int w = threadIdx.x >> 6, lane = threadIdx.x & 63;
    if (lane == 0) sb[w] = v;
    __syncthreads();
    float r = domax ? fmaxf(fmaxf(sb[0], sb[1]), fmaxf(sb[2], sb[3]))
                    : (sb[0] + sb[1] + sb[2] + sb[3]);
    __syncthreads();
    return r;
}

// canonicalize all inputs (bf16 or fp32, runtime-detected) -> fp32 master
__global__ __launch_bounds__(256) void convert_k(Ptrs20 ip, float* __restrict__ m){
    const int SZ[20]  = {786432,768,768,589824,768,589824,768,196608,256,196608,
                         768,768,1179648,768,589824,768,393216,512,768,1};
    const int OFF[20] = {OFF_X,OFF_GIN,OFF_BIN,OFF_CW1,OFF_CB1,OFF_CW2,OFF_CB2,OFF_CW3,OFF_CB3,OFF_EMB,
                         OFF_GE,OFF_BE,OFF_FW1,OFF_FB1,OFF_FW2,OFF_FB2,OFF_FW3,OFF_FB3,OFF_NW,OFF_NB};
    int t = blockIdx.y;
    int n = SZ[t];
    int i0 = (blockIdx.x * 256 + threadIdx.x) * 4;
    if (i0 >= n) return;
    bool isbf = (((const u16*)ip.p[1])[0] == 0x3F80u);
    float* dst = m + OFF[t] + i0;
    if (isbf){
        const u16* s = (const u16*)ip.p[t] + i0;
        #pragma unroll
        for (int e = 0; e < 4; e++) if (i0 + e < n) dst[e] = bf2f(s[e]);
    } else {
        const float* s = (const float*)ip.p[t] + i0;
        #pragma unroll
        for (int e = 0; e < 4; e++) if (i0 + e < n) dst[e] = s[e];
    }
}

// W (K x N) fp32 master -> Wt (N x K) bf16; SPL==2 also emits low part (w - bf16(w))
template<int SPL>
__global__ __launch_bounds__(256) void transpose_k(const float* __restrict__ W,
        u16* __restrict__ Wh, u16* __restrict__ Wl, int K, int N){
    __shared__ float t[32][33];
    int n0 = blockIdx.x * 32, k0 = blockIdx.y * 32;
    int tx = threadIdx.x & 31, ty = threadIdx.x >> 5;
    #pragma unroll
    for (int i = 0; i < 32; i += 8)
        t[ty + i][tx] = W[(size_t)(k0 + ty + i) * N + n0 + tx];
    __syncthreads();
    #pragma unroll
    for (int i = 0; i < 32; i += 8){
        float f = t[tx][ty + i];
        u16 h = f2bf(f);
        Wh[(size_t)(n0 + ty + i) * K + k0 + tx] = h;
        if (SPL == 2)
            Wl[(size_t)(n0 + ty + i) * K + k0 + tx] = f2bf(f - bf2f(h));
    }
}

// LayerNorm(x) -> xn (fp32 + bf16), and no_op head value per row
__global__ __launch_bounds__(256) void ln_x_k(const float* __restrict__ x,
        const float* __restrict__ g, const float* __restrict__ bb,
        const float* __restrict__ nW, const float* __restrict__ nb,
        float* __restrict__ xn_f32, u16* __restrict__ xn_bf, float* __restrict__ noop){
    __shared__ float sb[4];
    int b = blockIdx.x, tid = threadIdx.x;
    const float* xr = x + (size_t)b * CB;
    float v[3];
    #pragma unroll
    for (int i = 0; i < 3; i++) v[i] = xr[tid + i * 256];
    float mean = blockReduce(v[0] + v[1] + v[2], sb, false) * (1.0f / 768.0f);
    float d0 = v[0] - mean, d1 = v[1] - mean, d2 = v[2] - mean;
    float var = blockReduce(d0*d0 + d1*d1 + d2*d2, sb, false) * (1.0f / 768.0f);
    float inv = 1.0f / sqrtf(var + 1e-5f);
    float dot = 0.0f;
    #pragma unroll
    for (int i = 0; i < 3; i++){
        int c = tid + i * 256;
        float xi = (v[i] - mean) * inv * g[c] + bb[c];
        xn_f32[(size_t)b * CB + c] = xi;
        xn_bf[(size_t)b * CB + c] = f2bf(xi);
        dot += xi * nW[c];
    }
    dot = blockReduce(dot, sb, false);
    if (tid == 0) noop[b] = dot + nb[0];
}

// GEMM: Out(MxN) = act(A(MxK) @ B(KxN) + bias). Bth/Btl are N-major (NxK) bf16.
// ASPLIT==3: A fp32 split hi/lo/lo2. BSPLIT==2: B split hi/lo (near-fp32 product).
template<int ASPLIT, int BSPLIT, int ACT, int OUTBF>
__global__ __launch_bounds__(256) void gemm_k(const void* __restrict__ Ap,
        const u16* __restrict__ Bth, const u16* __restrict__ Btl,
        const float* __restrict__ bias, void* __restrict__ Outp, int M, int N, int K){
    constexpr int LDA = 40;   // 32 + 8 pad (bf16 elems)
    __shared__ u16 As[ASPLIT][128 * LDA];
    __shared__ u16 Bs[BSPLIT][64 * LDA];
    const int m0 = blockIdx.y * 128, n0 = blockIdx.x * 64;
    const int tid = threadIdx.x;
    const int w = tid >> 6, lane = tid & 63, lm = lane & 15, q = lane >> 4;
    f32x4 acc[2][4];
    #pragma unroll
    for (int i = 0; i < 2; i++)
        #pragma unroll
        for (int j = 0; j < 4; j++) acc[i][j] = (f32x4)(0.0f);
    const int ar = tid >> 1, ac = (tid & 1) * 16;   // A stage: 128 rows x 32 cols
    const int bn = tid >> 2, bc = (tid & 3) * 8;    // B stage: 64 rows x 32 cols

    for (int k0 = 0; k0 < K; k0 += 32){
        __syncthreads();
        if (ASPLIT == 3){
            const float* src = (const float*)Ap + (size_t)(m0 + ar) * K + k0 + ac;
            short hi[16], lo[16], l2[16];
            #pragma unroll
            for (int h = 0; h < 4; h++){
                float4 vv = ((const float4*)src)[h];
                float e4[4] = {vv.x, vv.y, vv.z, vv.w};
                #pragma unroll
                for (int e = 0; e < 4; e++){
                    float f = e4[e];
                    u16 hb = f2bf(f);  float fh = bf2f(hb);
                    float r1 = f - fh; u16 lb = f2bf(r1); float fl = bf2f(lb);
                    float r2 = r1 - fl; u16 qb = f2bf(r2);
                    hi[h*4+e] = (short)hb; lo[h*4+e] = (short)lb; l2[h*4+e] = (short)qb;
                }
            }
            *(s16x8*)&As[0][ar*LDA + ac]     = *(s16x8*)&hi[0];
            *(s16x8*)&As[0][ar*LDA + ac + 8] = *(s16x8*)&hi[8];
            *(s16x8*)&As[1][ar*LDA + ac]     = *(s16x8*)&lo[0];
            *(s16x8*)&As[1][ar*LDA + ac + 8] = *(s16x8*)&lo[8];
            *(s16x8*)&As[2][ar*LDA + ac]     = *(s16x8*)&l2[0];
            *(s16x8*)&As[2][ar*LDA + ac + 8] = *(s16x8*)&l2[8];
        } else {
            const u16* src = (const u16*)Ap + (size_t)(m0 + ar) * K + k0 + ac;
            *(s16x8*)&As[0][ar*LDA + ac]     = *(const s16x8*)(src);
            *(s16x8*)&As[0][ar*LDA + ac + 8] = *(const s16x8*)(src + 8);
        }
        *(s16x8*)&Bs[0][bn*LDA + bc] = *(const s16x8*)(Bth + (size_t)(n0 + bn) * K + k0 + bc);
        if (BSPLIT == 2)
            *(s16x8*)&Bs[1][bn*LDA + bc] = *(const s16x8*)(Btl + (size_t)(n0 + bn) * K + k0 + bc);
        __syncthreads();

        s16x8 afr[ASPLIT][2], bfr[BSPLIT][4];
        #pragma unroll
        for (int mt = 0; mt < 2; mt++)
            #pragma unroll
            for (int s = 0; s < ASPLIT; s++)
                afr[s][mt] = *(const s16x8*)&As[s][(w*32 + mt*16 + lm)*LDA + q*8];
        #pragma unroll
        for (int nt = 0; nt < 4; nt++)
            #pragma unroll
            for (int s = 0; s < BSPLIT; s++)
                bfr[s][nt] = *(const s16x8*)&Bs[s][(nt*16 + lm)*LDA + q*8];
        #pragma unroll
        for (int mt = 0; mt < 2; mt++)
            #pragma unroll
            for (int nt = 0; nt < 4; nt++){
                acc[mt][nt] = mfma16x16x32(afr[0][mt], bfr[0][nt], acc[mt][nt]);
                if (ASPLIT == 3){
                    acc[mt][nt] = mfma16x16x32(afr[1][mt], bfr[0][nt], acc[mt][nt]);
                    acc[mt][nt] = mfma16x16x32(afr[2][mt], bfr[0][nt], acc[mt][nt]);
                }
                if (BSPLIT == 2){
                    acc[mt][nt] = mfma16x16x32(afr[0][mt], bfr[1][nt], acc[mt][nt]);
                    if (ASPLIT == 3)
                        acc[mt][nt] = mfma16x16x32(afr[1][mt], bfr[1][nt], acc[mt][nt]);
                }
            }
    }
    #pragma unroll
    for (int nt = 0; nt < 4; nt++){
        int n = n0 + nt*16 + lm;
        float bv = bias[n];
        #pragma unroll
        for (int mt = 0; mt < 2; mt++){
            #pragma unroll
            for (int r = 0; r < 4; r++){
                int m = m0 + w*32 + mt*16 + q*4 + r;
                float vv = acc[mt][nt][r] + bv;
                if (ACT == 1) vv = gelu_f(vv);
                if (OUTBF) ((u16*)Outp)[(size_t)m * N + n] = f2bf(vv);
                else       ((float*)Outp)[(size_t)m * N + n] = vv;
            }
        }
    }
}

// per-row top-4 of coarse (ties -> smaller index)
__global__ __launch_bounds__(64) void topk_k(const float* __restrict__ coarse,
        int* __restrict__ idx, unsigned char* __restrict__ ksel){
    int b = blockIdx.x, lane = threadIdx.x;
    const float* cr = coarse + (size_t)b * NB;
    float v[4]; int id[4];
    #pragma unroll
    for (int j = 0; j < 4; j++){ id[j] = lane + 64*j; v[j] = cr[id[j]]; }
    ((u32*)(ksel + (size_t)b * NB))[lane] = 0xFFFFFFFFu;
    __syncthreads();
    for (int k = 0; k < 4; k++){
        float bv = v[0]; int bi = id[0];
        #pragma unroll
        for (int j = 1; j < 4; j++)
            if (v[j] > bv || (v[j] == bv && id[j] < bi)){ bv = v[j]; bi = id[j]; }
        #pragma unroll
        for (int o = 32; o > 0; o >>= 1){
            float ov = __shfl_xor(bv, o, 64);
            int   oi = __shfl_xor(bi, o, 64);
            if (ov > bv || (ov == bv && oi < bi)){ bv = ov; bi = oi; }
        }
        if (lane == 0){ idx[b*4 + k] = bi; ksel[(size_t)b * NB + bi] = (unsigned char)k; }
        #pragma unroll
        for (int j = 0; j < 4; j++) if (id[j] == bi) v[j] = -INFINITY;
    }
}

// build fine_in rows: [ xn_bf16[b] | bf16(LN(emb[idx[bk]])) ]
__global__ __launch_bounds__(256) void finein_k(const int* __restrict__ idx,
        const float* __restrict__ emb, const float* __restrict__ ge, const float* __restrict__ be,
        const u16* __restrict__ xnb, u16* __restrict__ fin){
    __shared__ float sb[4];
    int bk = blockIdx.x, tid = threadIdx.x;
    int b = bk >> 2;
    int n = idx[bk];
    const float* er = emb + (size_t)n * CB;
    float v[3];
    #pragma unroll
    for (int i = 0; i < 3; i++) v[i] = er[tid + i * 256];
    float mean = blockReduce(v[0] + v[1] + v[2], sb, false) * (1.0f / 768.0f);
    float d0 = v[0] - mean, d1 = v[1] - mean, d2 = v[2] - mean;
    float var = blockReduce(d0*d0 + d1*d1 + d2*d2, sb, false) * (1.0f / 768.0f);
    float inv = 1.0f / sqrtf(var + 1e-5f);
    u16* dst = fin + (size_t)bk * (2 * CB);
    #pragma unroll
    for (int i = 0; i < 3; i++){
        int c = tid + i * 256;
        dst[c] = xnb[(size_t)b * CB + c];
        dst[CB + c] = f2bf((v[i] - mean) * inv * ge[c] + be[c]);
    }
}

// in-place: fine <- fine + log F - logsumexp(fine) per 512-row
__global__ __launch_bounds__(256) void upd_k(float* __restrict__ fine){
    __shared__ float sb[4];
    int bk = blockIdx.x, tid = threadIdx.x;
    float* fr = fine + (size_t)bk * FB;
    float a = fr[tid], b2 = fr[tid + 256];
    float mx = blockReduce(fmaxf(a, b2), sb, true);
    float es = expf(a - mx) + expf(b2 - mx);
    float ssum = blockReduce(es, sb, false);
    float off = LOGF - (mx + logf(ssum));
    fr[tid] = a + off;
    fr[tid + 256] = b2 + off;
}

// assemble flat output: [no_op | permuted (coarse - logF + scatter(upd))]
// output dtype follows input dtype (runtime flag from g_in bit pattern)
__global__ __launch_bounds__(256) void out_k(const float* __restrict__ coarse,
        const float* __restrict__ upd, const unsigned char* __restrict__ ksel,
        const float* __restrict__ noop, const void* __restrict__ g_in_raw,
        void* __restrict__ outp){
    u32 g0 = ((u32)blockIdx.x * 256u + (u32)threadIdx.x) * 8u;
    const u32 total = (u32)BATCH * (u32)OUTC;
    if (g0 >= total) return;
    bool isbf = (((const u16*)g_in_raw)[0] == 0x3F80u);
    float vals[8];
    #pragma unroll
    for (int e = 0; e < 8; e++){
        u32 gg = g0 + (u32)e;
        u32 qq = gg >> 17;                       // div by 131073 = 2^17 + 1
        int rr = (int)(gg & 131071u) - (int)qq;
        if (rr < 0){ qq -= 1u; rr += 131073; }
        int b = (int)qq;
        float val;
        if (rr == 0){
            val = noop[b];
        } else {
            int j = rr - 1;
            int ch = j >> 13;
            int rem = j & 8191;
            int fh = rem >> 9, cw = (rem >> 5) & 15, ff = rem & 31;
            int n = (ch << 4) + cw;
            val = coarse[(size_t)b * NB + n] - LOGF;
            int ks = ksel[(size_t)b * NB + n];
            if (ks != 255) val += upd[(((size_t)b * 4 + ks) << 9) + (fh << 5) + ff];
        }
        vals[e] = val;
    }
    if (isbf){
        u16 res[8];
        #pragma unroll
        for (int e = 0; e < 8; e++) res[e] = f2bf(vals[e]);
        *(s16x8*)((u16*)outp + g0) = *(s16x8*)res;
    } else {
        float* of = (float*)outp + g0;
        *(float4*)(of)     = make_float4(vals[0], vals[1], vals[2], vals[3]);
        *(float4*)(of + 4) = make_float4(vals[4], vals[5], vals[6], vals[7]);
    }
}

extern "C" void kernel_launch(void* const* d_in, const int* in_sizes, int n_in,
                              void* d_out, int out_size, void* d_ws, size_t ws_size,
                              hipStream_t stream){
    (void)in_sizes; (void)n_in; (void)out_size; (void)ws_size;
    char* ws = (char*)d_ws;
    size_t off = 0;
    auto alloc = [&](size_t bytes){ void* p = ws + off; off += (bytes + 255) & ~(size_t)255; return p; };

    float* master = (float*)alloc((size_t)MASTER_TOTAL * 4);
    u16*   xn_bf  = (u16*)  alloc((size_t)1024*768*2);
    u16*   fin    = (u16*)  alloc((size_t)4096*1536*2);   // xn_f32 (3MB) aliases front
    float* fine   = (float*)alloc((size_t)4096*512*4);    // h1 (3MB) aliases front
    u16*   gg1    = (u16*)  alloc((size_t)4096*768*2);    // h2 (3MB) aliases front
    u16*   gg2    = (u16*)  alloc((size_t)4096*768*2);
    float* coarse = (float*)alloc((size_t)1024*256*4);
    int*   idx    = (int*)  alloc((size_t)1024*4*4);
    unsigned char* ksel = (unsigned char*)alloc((size_t)1024*256);
    float* noop   = (float*)alloc((size_t)1024*4);
    u16* cW1th = (u16*)alloc((size_t)768*768*2);
    u16* cW1tl = (u16*)alloc((size_t)768*768*2);
    u16* cW2th = (u16*)alloc((size_t)768*768*2);
    u16* cW2tl = (u16*)alloc((size_t)768*768*2);
    u16* cW3th = (u16*)alloc((size_t)768*256*2);
    u16* cW3tl = (u16*)alloc((size_t)768*256*2);
    u16* fW1t  = (u16*)alloc((size_t)1536*768*2);
    u16* fW2t  = (u16*)alloc((size_t)768*768*2);
    u16* fW3t  = (u16*)alloc((size_t)768*512*2);

    float* xn_f32 = (float*)fin;    // dead before finein_k writes fin
    float* h1     = (float*)fine;   // dead before fine gemm3 writes fine
    float* h2     = (float*)gg1;    // dead before fine gemm1 writes gg1

    Ptrs20 ip;
    for (int i = 0; i < 20; i++) ip.p[i] = d_in[i];

    // canonicalize inputs -> fp32 master (dtype auto-detected from g_in == ones)
    convert_k<<<dim3(1152, 20), 256, 0, stream>>>(ip, master);

    // weight transposes to N-major; coarse weights split hi/lo for accuracy
    transpose_k<2><<<dim3(24, 24), 256, 0, stream>>>(master + OFF_CW1, cW1th, cW1tl, 768, 768);
    transpose_k<2><<<dim3(24, 24), 256, 0, stream>>>(master + OFF_CW2, cW2th, cW2tl, 768, 768);
    transpose_k<2><<<dim3( 8, 24), 256, 0, stream>>>(master + OFF_CW3, cW3th, cW3tl, 768, 256);
    transpose_k<1><<<dim3(24, 48), 256, 0, stream>>>(master + OFF_FW1, fW1t, nullptr, 1536, 768);
    transpose_k<1><<<dim3(24, 24), 256, 0, stream>>>(master + OFF_FW2, fW2t, nullptr, 768, 768);
    transpose_k<1><<<dim3(16, 24), 256, 0, stream>>>(master + OFF_FW3, fW3t, nullptr, 768, 512);

    ln_x_k<<<1024, 256, 0, stream>>>(master + OFF_X, master + OFF_GIN, master + OFF_BIN,
                                     master + OFF_NW, master + OFF_NB, xn_f32, xn_bf, noop);

    // coarse MLP: A split-3 x B split-2 bf16 MFMA (near-fp32) for stable top-k
    gemm_k<3,2,1,0><<<dim3(12, 8), 256, 0, stream>>>(xn_f32, cW1th, cW1tl, master + OFF_CB1, h1, 1024, 768, 768);
    gemm_k<3,2,1,0><<<dim3(12, 8), 256, 0, stream>>>(h1,     cW2th, cW2tl, master + OFF_CB2, h2, 1024, 768, 768);
    gemm_k<3,2,0,0><<<dim3( 4, 8), 256, 0, stream>>>(h2,     cW3th, cW3tl, master + OFF_CB3, coarse, 1024, 256, 768);

    topk_k<<<1024, 64, 0, stream>>>(coarse, idx, ksel);
    finein_k<<<4096, 256, 0, stream>>>(idx, master + OFF_EMB, master + OFF_GE, master + OFF_BE, xn_bf, fin);

    // fine MLP: plain bf16 MFMA
    gemm_k<1,1,1,1><<<dim3(12, 32), 256, 0, stream>>>(fin, fW1t, nullptr, master + OFF_FB1, gg1, 4096, 768, 1536);
    gemm_k<1,1,1,1><<<dim3(12, 32), 256, 0, stream>>>(gg1, fW2t, nullptr, master + OFF_FB2, gg2, 4096, 768, 768);
    gemm_k<1,1,0,0><<<dim3( 8, 32), 256, 0, stream>>>(gg2, fW3t, nullptr, master + OFF_FB3, fine, 4096, 512, 768);

    upd_k<<<4096, 256, 0, stream>>>(fine);

    u32 total_chunks = ((u32)BATCH * (u32)OUTC) / 8u;
    u32 blocks = (total_chunks + 255u) / 256u;
    out_k<<<blocks, 256, 0, stream>>>(coarse, fine, ksel, noop, d_in[1], d_out);
}

// Round 3
// 840.121 us; speedup vs baseline: 1.0404x; 1.0404x over previous
//
#include <hip/hip_runtime.h>
#include <hip/hip_bf16.h>
#include <math.h>

typedef unsigned short u16;
typedef unsigned int   u32;
typedef __attribute__((ext_vector_type(8))) short s16x8;
typedef __attribute__((ext_vector_type(4))) float f32x4;

#define CB 768
#define NB 256
#define FB 512
#define BATCH 1024
#define OUTC 131073
#define LOGF 6.2383246250395077f

__device__ __forceinline__ u16 f2bf(float f){
    u32 u = __float_as_uint(f);
    u32 r = u + 0x7FFFu + ((u >> 16) & 1u);
    return (u16)(r >> 16);
}
__device__ __forceinline__ float bf2f(u16 s){ return __uint_as_float(((u32)s) << 16); }
__device__ __forceinline__ bool probe_bf(const void* g){ return ((const u16*)g)[0] == 0x3F80u; }
__device__ __forceinline__ float loadraw(const void* p, size_t i, bool isbf){
    return isbf ? bf2f(((const u16*)p)[i]) : ((const float*)p)[i];
}
__device__ __forceinline__ void split3(float f, u16& h, u16& l, u16& q){
    h = f2bf(f); float r1 = f - bf2f(h);
    l = f2bf(r1); float r2 = r1 - bf2f(l);
    q = f2bf(r2);
}
__device__ __forceinline__ float gelu_f(float x){
    return 0.5f * x * (1.0f + tanhf(0.7978845608028654f * (x + 0.044715f * x * x * x)));
}
__device__ __forceinline__ f32x4 mfma16x16x32(s16x8 a, s16x8 b, f32x4 c){
    return __builtin_amdgcn_mfma_f32_16x16x32_bf16(a, b, c, 0, 0, 0);
}

__device__ __forceinline__ float blockReduce(float v, float* sb, bool domax){
    #pragma unroll
    for (int o = 32; o > 0; o >>= 1){
        float ov = __shfl_down(v, o, 64);
        v = domax ? fmaxf(v, ov) : (v + ov);
    }
    int w = threadIdx.x >> 6, lane = threadIdx.x & 63;
    if (lane == 0) sb[w] = v;
    __syncthreads();
    float r = domax ? fmaxf(fmaxf(sb[0], sb[1]), fmaxf(sb[2], sb[3]))
                    : (sb[0] + sb[1] + sb[2] + sb[3]);
    __syncthreads();
    return r;
}

// ---- one launch for all 6 weight transposes: raw (KxN) -> N-major bf16 planes
struct TransDesc { const void* src; u16* dh; u16* dl; int K; int N; int start; int tilesX; };
struct TD6 { TransDesc d[6]; };

__global__ __launch_bounds__(256) void transpose_all_k(TD6 td, const void* ginp){
    bool isbf = probe_bf(ginp);
    int blk = blockIdx.x;
    int e = 0;
    #pragma unroll
    for (int i = 1; i < 6; i++) if (blk >= td.d[i].start) e = i;
    TransDesc d = td.d[e];
    int rel = blk - d.start;
    int n0 = (rel % d.tilesX) * 32;
    int k0 = (rel / d.tilesX) * 32;
    __shared__ float t[32][33];
    int tx = threadIdx.x & 31, ty = threadIdx.x >> 5;
    #pragma unroll
    for (int i = 0; i < 32; i += 8)
        t[ty + i][tx] = loadraw(d.src, (size_t)(k0 + ty + i) * d.N + n0 + tx, isbf);
    __syncthreads();
    #pragma unroll
    for (int i = 0; i < 32; i += 8){
        float f = t[tx][ty + i];
        u16 h = f2bf(f);
        d.dh[(size_t)(n0 + ty + i) * d.K + k0 + tx] = h;
        if (d.dl)
            d.dl[(size_t)(n0 + ty + i) * d.K + k0 + tx] = f2bf(f - bf2f(h));
    }
}

// LayerNorm(x) -> 3 bf16 split planes, plus no_op head value per row
__global__ __launch_bounds__(256) void ln_x_k(const void* x, const void* g, const void* bb,
        const void* nW, const void* nb, const void* ginp,
        u16* __restrict__ xh, u16* __restrict__ xl, u16* __restrict__ xq,
        float* __restrict__ noop){
    __shared__ float sb[4];
    bool isbf = probe_bf(ginp);
    int b = blockIdx.x, tid = threadIdx.x;
    float v[3];
    #pragma unroll
    for (int i = 0; i < 3; i++) v[i] = loadraw(x, (size_t)b * CB + tid + i * 256, isbf);
    float mean = blockReduce(v[0] + v[1] + v[2], sb, false) * (1.0f / 768.0f);
    float d0 = v[0] - mean, d1 = v[1] - mean, d2 = v[2] - mean;
    float var = blockReduce(d0*d0 + d1*d1 + d2*d2, sb, false) * (1.0f / 768.0f);
    float inv = 1.0f / sqrtf(var + 1e-5f);
    float dot = 0.0f;
    #pragma unroll
    for (int i = 0; i < 3; i++){
        int c = tid + i * 256;
        float xi = (v[i] - mean) * inv * loadraw(g, c, isbf) + loadraw(bb, c, isbf);
        u16 h, l, q; split3(xi, h, l, q);
        size_t o = (size_t)b * CB + c;
        xh[o] = h; xl[o] = l; xq[o] = q;
        dot += xi * loadraw(nW, c, isbf);
    }
    dot = blockReduce(dot, sb, false);
    if (tid == 0) noop[b] = dot + loadraw(nb, 0, isbf);
}

// GEMM: Out(MxN) = act(A @ B + bias); A given as 1 or 3 bf16 planes (MxK),
// B as 1 or 2 N-major bf16 planes. OUTMODE: 0=f32, 1=bf16, 2=split3 planes.
template<int ASPLIT, int BSPLIT, int ACT, int OUTMODE>
__global__ __launch_bounds__(256) void gemm_k(
        const u16* __restrict__ Ah, const u16* __restrict__ Al, const u16* __restrict__ Aq,
        const u16* __restrict__ Bth, const u16* __restrict__ Btl,
        const void* __restrict__ bias, const void* __restrict__ ginp,
        void* __restrict__ o0, void* __restrict__ o1, void* __restrict__ o2,
        int M, int N, int K){
    constexpr int LDA = 40;   // 32 + 8 pad (bf16 elems)
    __shared__ u16 As[ASPLIT][128 * LDA];
    __shared__ u16 Bs[BSPLIT][64 * LDA];
    bool isbf = probe_bf(ginp);
    const int m0 = blockIdx.y * 128, n0 = blockIdx.x * 64;
    const int tid = threadIdx.x;
    const int w = tid >> 6, lane = tid & 63, lm = lane & 15, q = lane >> 4;
    f32x4 acc[2][4];
    #pragma unroll
    for (int i = 0; i < 2; i++)
        #pragma unroll
        for (int j = 0; j < 4; j++) acc[i][j] = (f32x4)(0.0f);
    const int ar = tid >> 1, ac = (tid & 1) * 16;   // A stage: 128 rows x 32 cols
    const int bn = tid >> 2, bc = (tid & 3) * 8;    // B stage: 64 rows x 32 cols

    for (int k0 = 0; k0 < K; k0 += 32){
        __syncthreads();
        {
            const u16* s0 = Ah + (size_t)(m0 + ar) * K + k0 + ac;
            *(s16x8*)&As[0][ar*LDA + ac]     = *(const s16x8*)(s0);
            *(s16x8*)&As[0][ar*LDA + ac + 8] = *(const s16x8*)(s0 + 8);
            if (ASPLIT == 3){
                const u16* s1 = Al + (size_t)(m0 + ar) * K + k0 + ac;
                *(s16x8*)&As[1][ar*LDA + ac]     = *(const s16x8*)(s1);
                *(s16x8*)&As[1][ar*LDA + ac + 8] = *(const s16x8*)(s1 + 8);
                const u16* s2 = Aq + (size_t)(m0 + ar) * K + k0 + ac;
                *(s16x8*)&As[2][ar*LDA + ac]     = *(const s16x8*)(s2);
                *(s16x8*)&As[2][ar*LDA + ac + 8] = *(const s16x8*)(s2 + 8);
            }
        }
        *(s16x8*)&Bs[0][bn*LDA + bc] = *(const s16x8*)(Bth + (size_t)(n0 + bn) * K + k0 + bc);
        if (BSPLIT == 2)
            *(s16x8*)&Bs[1][bn*LDA + bc] = *(const s16x8*)(Btl + (size_t)(n0 + bn) * K + k0 + bc);
        __syncthreads();

        s16x8 afr[ASPLIT][2], bfr[BSPLIT][4];
        #pragma unroll
        for (int mt = 0; mt < 2; mt++)
            #pragma unroll
            for (int s = 0; s < ASPLIT; s++)
                afr[s][mt] = *(const s16x8*)&As[s][(w*32 + mt*16 + lm)*LDA + q*8];
        #pragma unroll
        for (int nt = 0; nt < 4; nt++)
            #pragma unroll
            for (int s = 0; s < BSPLIT; s++)
                bfr[s][nt] = *(const s16x8*)&Bs[s][(nt*16 + lm)*LDA + q*8];
        #pragma unroll
        for (int mt = 0; mt < 2; mt++)
            #pragma unroll
            for (int nt = 0; nt < 4; nt++){
                acc[mt][nt] = mfma16x16x32(afr[0][mt], bfr[0][nt], acc[mt][nt]);
                if (ASPLIT == 3){
                    acc[mt][nt] = mfma16x16x32(afr[1][mt], bfr[0][nt], acc[mt][nt]);
                    acc[mt][nt] = mfma16x16x32(afr[2][mt], bfr[0][nt], acc[mt][nt]);
                }
                if (BSPLIT == 2){
                    acc[mt][nt] = mfma16x16x32(afr[0][mt], bfr[1][nt], acc[mt][nt]);
                    if (ASPLIT == 3)
                        acc[mt][nt] = mfma16x16x32(afr[1][mt], bfr[1][nt], acc[mt][nt]);
                }
            }
    }
    #pragma unroll
    for (int nt = 0; nt < 4; nt++){
        int n = n0 + nt*16 + lm;
        float bv = loadraw(bias, n, isbf);
        #pragma unroll
        for (int mt = 0; mt < 2; mt++){
            #pragma unroll
            for (int r = 0; r < 4; r++){
                int m = m0 + w*32 + mt*16 + q*4 + r;
                float vv = acc[mt][nt][r] + bv;
                if (ACT == 1) vv = gelu_f(vv);
                size_t o = (size_t)m * N + n;
                if (OUTMODE == 0)      ((float*)o0)[o] = vv;
                else if (OUTMODE == 1) ((u16*)o0)[o] = f2bf(vv);
                else {
                    u16 h, l, qq; split3(vv, h, l, qq);
                    ((u16*)o0)[o] = h; ((u16*)o1)[o] = l; ((u16*)o2)[o] = qq;
                }
            }
        }
    }
}

// per-row top-4 of coarse (ties -> smaller index)
__global__ __launch_bounds__(64) void topk_k(const float* __restrict__ coarse,
        int* __restrict__ idx, unsigned char* __restrict__ ksel){
    int b = blockIdx.x, lane = threadIdx.x;
    const float* cr = coarse + (size_t)b * NB;
    float v[4]; int id[4];
    #pragma unroll
    for (int j = 0; j < 4; j++){ id[j] = lane + 64*j; v[j] = cr[id[j]]; }
    ((u32*)(ksel + (size_t)b * NB))[lane] = 0xFFFFFFFFu;
    __syncthreads();
    for (int k = 0; k < 4; k++){
        float bv = v[0]; int bi = id[0];
        #pragma unroll
        for (int j = 1; j < 4; j++)
            if (v[j] > bv || (v[j] == bv && id[j] < bi)){ bv = v[j]; bi = id[j]; }
        #pragma unroll
        for (int o = 32; o > 0; o >>= 1){
            float ov = __shfl_xor(bv, o, 64);
            int   oi = __shfl_xor(bi, o, 64);
            if (ov > bv || (ov == bv && oi < bi)){ bv = ov; bi = oi; }
        }
        if (lane == 0){ idx[b*4 + k] = bi; ksel[(size_t)b * NB + bi] = (unsigned char)k; }
        #pragma unroll
        for (int j = 0; j < 4; j++) if (id[j] == bi) v[j] = -INFINITY;
    }
}

// build fine_in rows: [ bf16(xn)[b] | bf16(LN(emb[idx[bk]])) ]
__global__ __launch_bounds__(256) void finein_k(const int* __restrict__ idx,
        const void* __restrict__ emb, const void* __restrict__ ge, const void* __restrict__ be,
        const void* __restrict__ ginp, const u16* __restrict__ xh, u16* __restrict__ fin){
    __shared__ float sb[4];
    bool isbf = probe_bf(ginp);
    int bk = blockIdx.x, tid = threadIdx.x;
    int b = bk >> 2;
    int n = idx[bk];
    float v[3];
    #pragma unroll
    for (int i = 0; i < 3; i++) v[i] = loadraw(emb, (size_t)n * CB + tid + i * 256, isbf);
    float mean = blockReduce(v[0] + v[1] + v[2], sb, false) * (1.0f / 768.0f);
    float d0 = v[0] - mean, d1 = v[1] - mean, d2 = v[2] - mean;
    float var = blockReduce(d0*d0 + d1*d1 + d2*d2, sb, false) * (1.0f / 768.0f);
    float inv = 1.0f / sqrtf(var + 1e-5f);
    u16* dst = fin + (size_t)bk * (2 * CB);
    #pragma unroll
    for (int i = 0; i < 3; i++){
        int c = tid + i * 256;
        dst[c] = xh[(size_t)b * CB + c];
        dst[CB + c] = f2bf((v[i] - mean) * inv * loadraw(ge, c, isbf) + loadraw(be, c, isbf));
    }
}

// per fine-row offset: logF - logsumexp(row); one wave per row
__global__ __launch_bounds__(256) void updoff_k(const float* __restrict__ fine,
        float* __restrict__ offs){
    int row = blockIdx.x * 4 + (threadIdx.x >> 6);
    int lane = threadIdx.x & 63;
    const float* fr = fine + (size_t)row * FB;
    float v[8];
    #pragma unroll
    for (int j = 0; j < 8; j++) v[j] = fr[lane + 64*j];
    float mx = v[0];
    #pragma unroll
    for (int j = 1; j < 8; j++) mx = fmaxf(mx, v[j]);
    #pragma unroll
    for (int o = 32; o > 0; o >>= 1) mx = fmaxf(mx, __shfl_xor(mx, o, 64));
    float es = 0.0f;
    #pragma unroll
    for (int j = 0; j < 8; j++) es += expf(v[j] - mx);
    #pragma unroll
    for (int o = 32; o > 0; o >>= 1) es += __shfl_xor(es, o, 64);
    if (lane == 0) offs[row] = LOGF - (mx + logf(es));
}

// assemble flat output: [no_op | permuted (coarse - logF + scatter(fine + off))]
__global__ __launch_bounds__(256) void out_k(const float* __restrict__ coarse,
        const float* __restrict__ fine, const float* __restrict__ offs,
        const unsigned char* __restrict__ ksel, const float* __restrict__ noop,
        const void* __restrict__ ginp, void* __restrict__ outp){
    u32 g0 = ((u32)blockIdx.x * 256u + (u32)threadIdx.x) * 8u;
    const u32 total = (u32)BATCH * (u32)OUTC;
    if (g0 >= total) return;
    bool isbf = probe_bf(ginp);
    float vals[8];
    #pragma unroll
    for (int e = 0; e < 8; e++){
        u32 gg = g0 + (u32)e;
        u32 qq = gg >> 17;                       // div by 131073 = 2^17 + 1
        int rr = (int)(gg & 131071u) - (int)qq;
        if (rr < 0){ qq -= 1u; rr += 131073; }
        int b = (int)qq;
        float val;
        if (rr == 0){
            val = noop[b];
        } else {
            int j = rr - 1;
            int ch = j >> 13;
            int rem = j & 8191;
            int fh = rem >> 9, cw = (rem >> 5) & 15, ff = rem & 31;
            int n = (ch << 4) + cw;
            val = coarse[(size_t)b * NB + n] - LOGF;
            int ks = ksel[(size_t)b * NB + n];
            if (ks != 255){
                int fr = b * 4 + ks;
                val += fine[((size_t)fr << 9) + (fh << 5) + ff] + offs[fr];
            }
        }
        vals[e] = val;
    }
    if (isbf){
        u16 res[8];
        #pragma unroll
        for (int e = 0; e < 8; e++) res[e] = f2bf(vals[e]);
        *(s16x8*)((u16*)outp + g0) = *(s16x8*)res;
    } else {
        float* of = (float*)outp + g0;
        *(float4*)(of)     = make_float4(vals[0], vals[1], vals[2], vals[3]);
        *(float4*)(of + 4) = make_float4(vals[4], vals[5], vals[6], vals[7]);
    }
}

extern "C" void kernel_launch(void* const* d_in, const int* in_sizes, int n_in,
                              void* d_out, int out_size, void* d_ws, size_t ws_size,
                              hipStream_t stream){
    (void)in_sizes; (void)n_in; (void)out_size; (void)ws_size;
    char* ws = (char*)d_ws;
    size_t off = 0;
    auto alloc = [&](size_t bytes){ void* p = ws + off; off += (bytes + 255) & ~(size_t)255; return p; };

    u16* xh  = (u16*)alloc((size_t)1024*768*2);
    u16* xl  = (u16*)alloc((size_t)1024*768*2);
    u16* xq  = (u16*)alloc((size_t)1024*768*2);
    u16* h1h = (u16*)alloc((size_t)1024*768*2);
    u16* h1l = (u16*)alloc((size_t)1024*768*2);
    u16* h1q = (u16*)alloc((size_t)1024*768*2);
    u16* h2h = (u16*)alloc((size_t)1024*768*2);
    u16* h2l = (u16*)alloc((size_t)1024*768*2);
    u16* h2q = (u16*)alloc((size_t)1024*768*2);
    float* coarse = (float*)alloc((size_t)1024*256*4);
    int*   idx    = (int*)  alloc((size_t)1024*4*4);
    unsigned char* ksel = (unsigned char*)alloc((size_t)1024*256);
    float* noop   = (float*)alloc((size_t)1024*4);
    float* offs   = (float*)alloc((size_t)4096*4);
    u16*   fin    = (u16*)  alloc((size_t)4096*1536*2);
    u16*   gg1    = (u16*)  alloc((size_t)4096*768*2);
    u16*   gg2    = (u16*)  alloc((size_t)4096*768*2);
    float* fine   = (float*)alloc((size_t)4096*512*4);
    u16* cW1th = (u16*)alloc((size_t)768*768*2);
    u16* cW1tl = (u16*)alloc((size_t)768*768*2);
    u16* cW2th = (u16*)alloc((size_t)768*768*2);
    u16* cW2tl = (u16*)alloc((size_t)768*768*2);
    u16* cW3th = (u16*)alloc((size_t)768*256*2);
    u16* cW3tl = (u16*)alloc((size_t)768*256*2);
    u16* fW1t  = (u16*)alloc((size_t)1536*768*2);
    u16* fW2t  = (u16*)alloc((size_t)768*768*2);
    u16* fW3t  = (u16*)alloc((size_t)768*512*2);

    const void* ginp = d_in[1];

    // all weight transposes in one launch
    TD6 td;
    td.d[0] = { d_in[3],  cW1th, cW1tl,  768, 768,    0, 24 };  // 576 tiles
    td.d[1] = { d_in[5],  cW2th, cW2tl,  768, 768,  576, 24 };  // 576
    td.d[2] = { d_in[7],  cW3th, cW3tl,  768, 256, 1152,  8 };  // 192
    td.d[3] = { d_in[12], fW1t,  nullptr,1536, 768, 1344, 24 }; // 1152
    td.d[4] = { d_in[14], fW2t,  nullptr, 768, 768, 2496, 24 }; // 576
    td.d[5] = { d_in[16], fW3t,  nullptr, 768, 512, 3072, 16 }; // 384 -> 3456
    transpose_all_k<<<3456, 256, 0, stream>>>(td, ginp);

    ln_x_k<<<1024, 256, 0, stream>>>(d_in[0], d_in[1], d_in[2], d_in[18], d_in[19],
                                     ginp, xh, xl, xq, noop);

    // coarse MLP: A split-3 x B split-2 (5 MFMA terms, near-fp32) for stable top-k;
    // epilogues emit next layer's split planes directly (no in-loop splitting)
    gemm_k<3,2,1,2><<<dim3(12, 8), 256, 0, stream>>>(xh, xl, xq, cW1th, cW1tl,
            d_in[4], ginp, h1h, h1l, h1q, 1024, 768, 768);
    gemm_k<3,2,1,2><<<dim3(12, 8), 256, 0, stream>>>(h1h, h1l, h1q, cW2th, cW2tl,
            d_in[6], ginp, h2h, h2l, h2q, 1024, 768, 768);
    gemm_k<3,2,0,0><<<dim3( 4, 8), 256, 0, stream>>>(h2h, h2l, h2q, cW3th, cW3tl,
            d_in[8], ginp, coarse, nullptr, nullptr, 1024, 256, 768);

    topk_k<<<1024, 64, 0, stream>>>(coarse, idx, ksel);
    finein_k<<<4096, 256, 0, stream>>>(idx, d_in[9], d_in[10], d_in[11], ginp, xh, fin);

    // fine MLP: plain bf16 MFMA
    gemm_k<1,1,1,1><<<dim3(12, 32), 256, 0, stream>>>(fin, nullptr, nullptr, fW1t, nullptr,
            d_in[13], ginp, gg1, nullptr, nullptr, 4096, 768, 1536);
    gemm_k<1,1,1,1><<<dim3(12, 32), 256, 0, stream>>>(gg1, nullptr, nullptr, fW2t, nullptr,
            d_in[15], ginp, gg2, nullptr, nullptr, 4096, 768, 768);
    gemm_k<1,1,0,0><<<dim3( 8, 32), 256, 0, stream>>>(gg2, nullptr, nullptr, fW3t, nullptr,
            d_in[17], ginp, fine, nullptr, nullptr, 4096, 512, 768);

    updoff_k<<<1024, 256, 0, stream>>>(fine, offs);

    u32 total_chunks = ((u32)BATCH * (u32)OUTC) / 8u;
    u32 blocks = (total_chunks + 255u) / 256u;
    out_k<<<blocks, 256, 0, stream>>>(coarse, fine, offs, ksel, noop, ginp, d_out);
}

// Round 4
// 815.885 us; speedup vs baseline: 1.0713x; 1.0297x over previous
//
#include <hip/hip_runtime.h>
#include <hip/hip_bf16.h>
#include <math.h>

typedef unsigned short u16;
typedef unsigned int   u32;
typedef __attribute__((ext_vector_type(8))) short s16x8;
typedef __attribute__((ext_vector_type(4))) float f32x4;

#define CB 768
#define NB 256
#define FB 512
#define BATCH 1024
#define OUTC 131073
#define LOGF 6.2383246250395077f

__device__ __forceinline__ u16 f2bf(float f){
    u32 u = __float_as_uint(f);
    u32 r = u + 0x7FFFu + ((u >> 16) & 1u);
    return (u16)(r >> 16);
}
__device__ __forceinline__ float bf2f(u16 s){ return __uint_as_float(((u32)s) << 16); }
__device__ __forceinline__ bool probe_bf(const void* g){ return ((const u16*)g)[0] == 0x3F80u; }
__device__ __forceinline__ float loadraw(const void* p, size_t i, bool isbf){
    return isbf ? bf2f(((const u16*)p)[i]) : ((const float*)p)[i];
}
__device__ __forceinline__ void split3(float f, u16& h, u16& l, u16& q){
    h = f2bf(f); float r1 = f - bf2f(h);
    l = f2bf(r1); float r2 = r1 - bf2f(l);
    q = f2bf(r2);
}
__device__ __forceinline__ float gelu_f(float x){
    return 0.5f * x * (1.0f + tanhf(0.7978845608028654f * (x + 0.044715f * x * x * x)));
}
__device__ __forceinline__ f32x4 mfma16x16x32(s16x8 a, s16x8 b, f32x4 c){
    return __builtin_amdgcn_mfma_f32_16x16x32_bf16(a, b, c, 0, 0, 0);
}

__device__ __forceinline__ float blockReduce(float v, float* sb, bool domax){
    #pragma unroll
    for (int o = 32; o > 0; o >>= 1){
        float ov = __shfl_down(v, o, 64);
        v = domax ? fmaxf(v, ov) : (v + ov);
    }
    int w = threadIdx.x >> 6, lane = threadIdx.x & 63;
    if (lane == 0) sb[w] = v;
    __syncthreads();
    float r = domax ? fmaxf(fmaxf(sb[0], sb[1]), fmaxf(sb[2], sb[3]))
                    : (sb[0] + sb[1] + sb[2] + sb[3]);
    __syncthreads();
    return r;
}

// ---------- prep: 6 weight transposes + LN(x)+noop + coarse/sumexp init, 1 launch
struct TransDesc { const void* src; u16* dh; u16* dl; int K; int N; int start; int tilesX; };
struct TD6 { TransDesc d[6]; };

#define T_TRANS 3456
#define T_LNEND 4480   // 3456 + 1024
#define T_CIEND 4496   // + 16 coarse-init blocks
#define T_GRID  4497   // + 1 sumexp-zero block

__global__ __launch_bounds__(256) void prep_k(TD6 td,
        const void* x, const void* g, const void* bb, const void* nW, const void* nb,
        const void* cb3, const void* ginp,
        u16* __restrict__ xh, u16* __restrict__ xl, u16* __restrict__ xq,
        float* __restrict__ noop, float* __restrict__ coarse, float* __restrict__ sumexp){
    __shared__ float t[32][33];
    __shared__ float sb[4];
    bool isbf = probe_bf(ginp);
    int blk = blockIdx.x, tid = threadIdx.x;
    if (blk < T_TRANS){
        int e = 0;
        #pragma unroll
        for (int i = 1; i < 6; i++) if (blk >= td.d[i].start) e = i;
        TransDesc d = td.d[e];
        int rel = blk - d.start;
        int n0 = (rel % d.tilesX) * 32;
        int k0 = (rel / d.tilesX) * 32;
        int tx = tid & 31, ty = tid >> 5;
        #pragma unroll
        for (int i = 0; i < 32; i += 8)
            t[ty + i][tx] = loadraw(d.src, (size_t)(k0 + ty + i) * d.N + n0 + tx, isbf);
        __syncthreads();
        #pragma unroll
        for (int i = 0; i < 32; i += 8){
            float f = t[tx][ty + i];
            u16 h = f2bf(f);
            d.dh[(size_t)(n0 + ty + i) * d.K + k0 + tx] = h;
            if (d.dl)
                d.dl[(size_t)(n0 + ty + i) * d.K + k0 + tx] = f2bf(f - bf2f(h));
        }
    } else if (blk < T_LNEND){
        int b = blk - T_TRANS;
        float v[3];
        #pragma unroll
        for (int i = 0; i < 3; i++) v[i] = loadraw(x, (size_t)b * CB + tid + i * 256, isbf);
        float mean = blockReduce(v[0] + v[1] + v[2], sb, false) * (1.0f / 768.0f);
        float d0 = v[0] - mean, d1 = v[1] - mean, d2 = v[2] - mean;
        float var = blockReduce(d0*d0 + d1*d1 + d2*d2, sb, false) * (1.0f / 768.0f);
        float inv = 1.0f / sqrtf(var + 1e-5f);
        float dot = 0.0f;
        #pragma unroll
        for (int i = 0; i < 3; i++){
            int c = tid + i * 256;
            float xi = (v[i] - mean) * inv * loadraw(g, c, isbf) + loadraw(bb, c, isbf);
            u16 h, l, q; split3(xi, h, l, q);
            size_t o = (size_t)b * CB + c;
            xh[o] = h; xl[o] = l; xq[o] = q;
            dot += xi * loadraw(nW, c, isbf);
        }
        dot = blockReduce(dot, sb, false);
        if (tid == 0) noop[b] = dot + loadraw(nb, 0, isbf);
    } else if (blk < T_CIEND){
        // coarse[b][n] = cb3[n]  (cg3 atomically accumulates partials on top)
        int base = (blk - T_LNEND) * 16384;
        #pragma unroll
        for (int j = 0; j < 64; j++){
            int i = base + j * 256 + tid;
            coarse[i] = loadraw(cb3, i & 255, isbf);
        }
    } else {
        #pragma unroll
        for (int j = 0; j < 16; j++) sumexp[j * 256 + tid] = 0.0f;
    }
}

// ---------- GEMM 128x64 tile, register-prefetch pipelined, optional split-K (gridDim.z)
// OUTMODE: 0=f32, 1=bf16, 2=split3 planes, 3=atomicAdd f32 (no bias/act),
//          4=f32 + per-row atomic sum of exp(val) into o1
template<int ASPLIT, int BSPLIT, int ACT, int OUTMODE>
__global__ __launch_bounds__(256) void gemm_k(
        const u16* __restrict__ Ah, const u16* __restrict__ Al, const u16* __restrict__ Aq,
        const u16* __restrict__ Bth, const u16* __restrict__ Btl,
        const void* __restrict__ bias, const void* __restrict__ ginp,
        void* __restrict__ o0, void* __restrict__ o1, void* __restrict__ o2,
        int M, int N, int K){
    constexpr int LDA = 40;   // 32 + 8 pad (bf16 elems)
    __shared__ u16 As[ASPLIT][128 * LDA];
    __shared__ u16 Bs[BSPLIT][64 * LDA];
    bool isbf = probe_bf(ginp);
    const int m0 = blockIdx.y * 128, n0 = blockIdx.x * 64;
    const int tid = threadIdx.x;
    const int w = tid >> 6, lane = tid & 63, lm = lane & 15, q = lane >> 4;
    const int kc = K / gridDim.z;
    const int kbeg = blockIdx.z * kc, kend = kbeg + kc;
    f32x4 acc[2][4];
    #pragma unroll
    for (int i = 0; i < 2; i++)
        #pragma unroll
        for (int j = 0; j < 4; j++) acc[i][j] = (f32x4)(0.0f);
    const int ar = tid >> 1, ac = (tid & 1) * 16;   // A stage: 128 rows x 32 cols
    const int bn = tid >> 2, bc = (tid & 3) * 8;    // B stage: 64 rows x 32 cols

    s16x8 pa[ASPLIT][2], pb[BSPLIT];
    auto load_regs = [&](int kk){
        const u16* s0 = Ah + (size_t)(m0 + ar) * K + kk + ac;
        pa[0][0] = *(const s16x8*)(s0);
        pa[0][1] = *(const s16x8*)(s0 + 8);
        if (ASPLIT == 3){
            const u16* s1 = Al + (size_t)(m0 + ar) * K + kk + ac;
            pa[1][0] = *(const s16x8*)(s1);
            pa[1][1] = *(const s16x8*)(s1 + 8);
            const u16* s2 = Aq + (size_t)(m0 + ar) * K + kk + ac;
            pa[2][0] = *(const s16x8*)(s2);
            pa[2][1] = *(const s16x8*)(s2 + 8);
        }
        pb[0] = *(const s16x8*)(Bth + (size_t)(n0 + bn) * K + kk + bc);
        if (BSPLIT == 2)
            pb[1] = *(const s16x8*)(Btl + (size_t)(n0 + bn) * K + kk + bc);
    };

    load_regs(kbeg);
    for (int k0 = kbeg; k0 < kend; k0 += 32){
        __syncthreads();
        #pragma unroll
        for (int s = 0; s < ASPLIT; s++){
            *(s16x8*)&As[s][ar*LDA + ac]     = pa[s][0];
            *(s16x8*)&As[s][ar*LDA + ac + 8] = pa[s][1];
        }
        #pragma unroll
        for (int s = 0; s < BSPLIT; s++)
            *(s16x8*)&Bs[s][bn*LDA + bc] = pb[s];
        __syncthreads();
        if (k0 + 32 < kend) load_regs(k0 + 32);   // in flight during compute

        s16x8 afr[ASPLIT][2], bfr[BSPLIT][4];
        #pragma unroll
        for (int mt = 0; mt < 2; mt++)
            #pragma unroll
            for (int s = 0; s < ASPLIT; s++)
                afr[s][mt] = *(const s16x8*)&As[s][(w*32 + mt*16 + lm)*LDA + q*8];
        #pragma unroll
        for (int nt = 0; nt < 4; nt++)
            #pragma unroll
            for (int s = 0; s < BSPLIT; s++)
                bfr[s][nt] = *(const s16x8*)&Bs[s][(nt*16 + lm)*LDA + q*8];
        #pragma unroll
        for (int mt = 0; mt < 2; mt++)
            #pragma unroll
            for (int nt = 0; nt < 4; nt++){
                acc[mt][nt] = mfma16x16x32(afr[0][mt], bfr[0][nt], acc[mt][nt]);
                if (ASPLIT == 3){
                    acc[mt][nt] = mfma16x16x32(afr[1][mt], bfr[0][nt], acc[mt][nt]);
                    acc[mt][nt] = mfma16x16x32(afr[2][mt], bfr[0][nt], acc[mt][nt]);
                }
                if (BSPLIT == 2){
                    acc[mt][nt] = mfma16x16x32(afr[0][mt], bfr[1][nt], acc[mt][nt]);
                    if (ASPLIT == 3)
                        acc[mt][nt] = mfma16x16x32(afr[1][mt], bfr[1][nt], acc[mt][nt]);
                }
            }
    }

    if (OUTMODE == 3){
        #pragma unroll
        for (int nt = 0; nt < 4; nt++){
            int n = n0 + nt*16 + lm;
            #pragma unroll
            for (int mt = 0; mt < 2; mt++)
                #pragma unroll
                for (int r = 0; r < 4; r++){
                    int m = m0 + w*32 + mt*16 + q*4 + r;
                    atomicAdd(&((float*)o0)[(size_t)m * N + n], acc[mt][nt][r]);
                }
        }
    } else if (OUTMODE == 4){
        #pragma unroll
        for (int mt = 0; mt < 2; mt++)
            #pragma unroll
            for (int r = 0; r < 4; r++){
                int m = m0 + w*32 + mt*16 + q*4 + r;
                float esum = 0.0f;
                #pragma unroll
                for (int nt = 0; nt < 4; nt++){
                    int n = n0 + nt*16 + lm;
                    float vv = acc[mt][nt][r] + loadraw(bias, n, isbf);
                    ((float*)o0)[(size_t)m * N + n] = vv;
                    esum += expf(vv);
                }
                #pragma unroll
                for (int o = 8; o > 0; o >>= 1) esum += __shfl_down(esum, o, 16);
                if (lm == 0) atomicAdd(&((float*)o1)[m], esum);
            }
    } else {
        #pragma unroll
        for (int nt = 0; nt < 4; nt++){
            int n = n0 + nt*16 + lm;
            float bv = loadraw(bias, n, isbf);
            #pragma unroll
            for (int mt = 0; mt < 2; mt++){
                #pragma unroll
                for (int r = 0; r < 4; r++){
                    int m = m0 + w*32 + mt*16 + q*4 + r;
                    float vv = acc[mt][nt][r] + bv;
                    if (ACT == 1) vv = gelu_f(vv);
                    size_t o = (size_t)m * N + n;
                    if (OUTMODE == 0)      ((float*)o0)[o] = vv;
                    else if (OUTMODE == 1) ((u16*)o0)[o] = f2bf(vv);
                    else {
                        u16 h, l, qq; split3(vv, h, l, qq);
                        ((u16*)o0)[o] = h; ((u16*)o1)[o] = l; ((u16*)o2)[o] = qq;
                    }
                }
            }
        }
    }
}

// ---------- fused top-4 + fine-input build (one block per batch row)
__global__ __launch_bounds__(256) void topkfine_k(const float* __restrict__ coarse,
        const void* __restrict__ emb, const void* __restrict__ ge, const void* __restrict__ be,
        const void* __restrict__ ginp, const u16* __restrict__ xh,
        u16* __restrict__ fin, unsigned char* __restrict__ ksel){
    __shared__ float sb[4];
    __shared__ float swv[4]; __shared__ int swi[4];
    __shared__ int sel4[4]; __shared__ int chosen_s;
    bool isbf = probe_bf(ginp);
    int b = blockIdx.x, tid = threadIdx.x;
    int w = tid >> 6, lane = tid & 63;
    float v = coarse[(size_t)b * NB + tid];
    ksel[(size_t)b * NB + tid] = (unsigned char)255;
    __syncthreads();
    for (int k = 0; k < 4; k++){
        float bv = v; int bi = tid;
        #pragma unroll
        for (int o = 32; o > 0; o >>= 1){
            float ov = __shfl_xor(bv, o, 64);
            int   oi = __shfl_xor(bi, o, 64);
            if (ov > bv || (ov == bv && oi < bi)){ bv = ov; bi = oi; }
        }
        if (lane == 0){ swv[w] = bv; swi[w] = bi; }
        __syncthreads();
        if (tid == 0){
            float cv = swv[0]; int ci = swi[0];
            #pragma unroll
            for (int j = 1; j < 4; j++)
                if (swv[j] > cv || (swv[j] == cv && swi[j] < ci)){ cv = swv[j]; ci = swi[j]; }
            sel4[k] = ci; chosen_s = ci;
            ksel[(size_t)b * NB + ci] = (unsigned char)k;
        }
        __syncthreads();
        if (tid == chosen_s) v = -INFINITY;
    }
    #pragma unroll 1
    for (int k = 0; k < 4; k++){
        int n = sel4[k];
        float vv[3];
        #pragma unroll
        for (int i = 0; i < 3; i++) vv[i] = loadraw(emb, (size_t)n * CB + tid + i * 256, isbf);
        float mean = blockReduce(vv[0] + vv[1] + vv[2], sb, false) * (1.0f / 768.0f);
        float d0 = vv[0] - mean, d1 = vv[1] - mean, d2 = vv[2] - mean;
        float var = blockReduce(d0*d0 + d1*d1 + d2*d2, sb, false) * (1.0f / 768.0f);
        float inv = 1.0f / sqrtf(var + 1e-5f);
        u16* dst = fin + ((size_t)b * 4 + k) * (2 * CB);
        #pragma unroll
        for (int i = 0; i < 3; i++){
            int c = tid + i * 256;
            dst[c] = xh[(size_t)b * CB + c];
            dst[CB + c] = f2bf((vv[i] - mean) * inv * loadraw(ge, c, isbf) + loadraw(be, c, isbf));
        }
    }
}

// ---------- assemble flat output
__global__ __launch_bounds__(256) void out_k(const float* __restrict__ coarse,
        const float* __restrict__ fine, const float* __restrict__ sumexp,
        const unsigned char* __restrict__ ksel, const float* __restrict__ noop,
        const void* __restrict__ ginp, void* __restrict__ outp){
    u32 g0 = ((u32)blockIdx.x * 256u + (u32)threadIdx.x) * 8u;
    const u32 total = (u32)BATCH * (u32)OUTC;
    if (g0 >= total) return;
    bool isbf = probe_bf(ginp);
    float vals[8];
    #pragma unroll
    for (int e = 0; e < 8; e++){
        u32 gg = g0 + (u32)e;
        u32 qq = gg >> 17;                       // div by 131073 = 2^17 + 1
        int rr = (int)(gg & 131071u) - (int)qq;
        if (rr < 0){ qq -= 1u; rr += 131073; }
        int b = (int)qq;
        float val;
        if (rr == 0){
            val = noop[b];
        } else {
            int j = rr - 1;
            int ch = j >> 13;
            int rem = j & 8191;
            int fh = rem >> 9, cw = (rem >> 5) & 15, ff = rem & 31;
            int n = (ch << 4) + cw;
            val = coarse[(size_t)b * NB + n] - LOGF;
            int ks = ksel[(size_t)b * NB + n];
            if (ks != 255){
                int fr = b * 4 + ks;
                val += fine[((size_t)fr << 9) + (fh << 5) + ff] + (LOGF - logf(sumexp[fr]));
            }
        }
        vals[e] = val;
    }
    if (isbf){
        u16 res[8];
        #pragma unroll
        for (int e = 0; e < 8; e++) res[e] = f2bf(vals[e]);
        *(s16x8*)((u16*)outp + g0) = *(s16x8*)res;
    } else {
        float* of = (float*)outp + g0;
        *(float4*)(of)     = make_float4(vals[0], vals[1], vals[2], vals[3]);
        *(float4*)(of + 4) = make_float4(vals[4], vals[5], vals[6], vals[7]);
    }
}

extern "C" void kernel_launch(void* const* d_in, const int* in_sizes, int n_in,
                              void* d_out, int out_size, void* d_ws, size_t ws_size,
                              hipStream_t stream){
    (void)in_sizes; (void)n_in; (void)out_size; (void)ws_size;
    char* ws = (char*)d_ws;
    size_t off = 0;
    auto alloc = [&](size_t bytes){ void* p = ws + off; off += (bytes + 255) & ~(size_t)255; return p; };

    u16* xh  = (u16*)alloc((size_t)1024*768*2);
    u16* xl  = (u16*)alloc((size_t)1024*768*2);
    u16* xq  = (u16*)alloc((size_t)1024*768*2);
    u16* h1h = (u16*)alloc((size_t)1024*768*2);
    u16* h1l = (u16*)alloc((size_t)1024*768*2);
    u16* h1q = (u16*)alloc((size_t)1024*768*2);
    u16* h2h = (u16*)alloc((size_t)1024*768*2);
    u16* h2l = (u16*)alloc((size_t)1024*768*2);
    u16* h2q = (u16*)alloc((size_t)1024*768*2);
    float* coarse = (float*)alloc((size_t)1024*256*4);
    unsigned char* ksel = (unsigned char*)alloc((size_t)1024*256);
    float* noop   = (float*)alloc((size_t)1024*4);
    float* sumexp = (float*)alloc((size_t)4096*4);
    u16*   fin    = (u16*)  alloc((size_t)4096*1536*2);
    u16*   gg1    = (u16*)  alloc((size_t)4096*768*2);
    u16*   gg2    = (u16*)  alloc((size_t)4096*768*2);
    float* fine   = (float*)alloc((size_t)4096*512*4);
    u16* cW1th = (u16*)alloc((size_t)768*768*2);
    u16* cW1tl = (u16*)alloc((size_t)768*768*2);
    u16* cW2th = (u16*)alloc((size_t)768*768*2);
    u16* cW2tl = (u16*)alloc((size_t)768*768*2);
    u16* cW3th = (u16*)alloc((size_t)768*256*2);
    u16* cW3tl = (u16*)alloc((size_t)768*256*2);
    u16* fW1t  = (u16*)alloc((size_t)1536*768*2);
    u16* fW2t  = (u16*)alloc((size_t)768*768*2);
    u16* fW3t  = (u16*)alloc((size_t)768*512*2);

    const void* ginp = d_in[1];

    TD6 td;
    td.d[0] = { d_in[3],  cW1th, cW1tl,  768, 768,    0, 24 };  // 576 tiles
    td.d[1] = { d_in[5],  cW2th, cW2tl,  768, 768,  576, 24 };  // 576
    td.d[2] = { d_in[7],  cW3th, cW3tl,  768, 256, 1152,  8 };  // 192
    td.d[3] = { d_in[12], fW1t,  nullptr,1536, 768, 1344, 24 }; // 1152
    td.d[4] = { d_in[14], fW2t,  nullptr, 768, 768, 2496, 24 }; // 576
    td.d[5] = { d_in[16], fW3t,  nullptr, 768, 512, 3072, 16 }; // 384 -> 3456

    // transposes + LN(x)+noop + coarse=bias init + sumexp=0, one launch
    prep_k<<<T_GRID, 256, 0, stream>>>(td, d_in[0], d_in[1], d_in[2], d_in[18], d_in[19],
                                       d_in[8], ginp, xh, xl, xq, noop, coarse, sumexp);

    // coarse MLP: A split-3 x B split-2 (5 MFMA terms, near-fp32) for stable top-k
    gemm_k<3,2,1,2><<<dim3(12, 8, 1), 256, 0, stream>>>(xh, xl, xq, cW1th, cW1tl,
            d_in[4], ginp, h1h, h1l, h1q, 1024, 768, 768);
    gemm_k<3,2,1,2><<<dim3(12, 8, 1), 256, 0, stream>>>(h1h, h1l, h1q, cW2th, cW2tl,
            d_in[6], ginp, h2h, h2l, h2q, 1024, 768, 768);
    // layer 3: split-K=6, atomic accumulate onto bias-initialized coarse
    gemm_k<3,2,0,3><<<dim3( 4, 8, 6), 256, 0, stream>>>(h2h, h2l, h2q, cW3th, cW3tl,
            nullptr, ginp, coarse, nullptr, nullptr, 1024, 256, 768);

    topkfine_k<<<1024, 256, 0, stream>>>(coarse, d_in[9], d_in[10], d_in[11], ginp, xh, fin, ksel);

    // fine MLP: plain bf16 MFMA; layer 3 epilogue accumulates per-row sum(exp)
    gemm_k<1,1,1,1><<<dim3(12, 32, 1), 256, 0, stream>>>(fin, nullptr, nullptr, fW1t, nullptr,
            d_in[13], ginp, gg1, nullptr, nullptr, 4096, 768, 1536);
    gemm_k<1,1,1,1><<<dim3(12, 32, 1), 256, 0, stream>>>(gg1, nullptr, nullptr, fW2t, nullptr,
            d_in[15], ginp, gg2, nullptr, nullptr, 4096, 768, 768);
    gemm_k<1,1,0,4><<<dim3( 8, 32, 1), 256, 0, stream>>>(gg2, nullptr, nullptr, fW3t, nullptr,
            d_in[17], ginp, fine, sumexp, nullptr, 4096, 512, 768);

    u32 total_chunks = ((u32)BATCH * (u32)OUTC) / 8u;
    u32 blocks = (total_chunks + 255u) / 256u;
    out_k<<<blocks, 256, 0, stream>>>(coarse, fine, sumexp, ksel, noop, ginp, d_out);
}

// Round 5
// 813.027 us; speedup vs baseline: 1.0751x; 1.0035x over previous
//
#include <hip/hip_runtime.h>
#include <hip/hip_bf16.h>
#include <math.h>

typedef unsigned short u16;
typedef unsigned int   u32;
typedef __attribute__((ext_vector_type(8))) short s16x8;
typedef __attribute__((ext_vector_type(4))) float f32x4;

#define CB 768
#define NB 256
#define FB 512
#define BATCH 1024
#define OUTC 131073
#define LOGF 6.2383246250395077f

__device__ __forceinline__ u16 f2bf(float f){
    u32 u = __float_as_uint(f);
    u32 r = u + 0x7FFFu + ((u >> 16) & 1u);
    return (u16)(r >> 16);
}
__device__ __forceinline__ float bf2f(u16 s){ return __uint_as_float(((u32)s) << 16); }
__device__ __forceinline__ bool probe_bf(const void* g){ return ((const u16*)g)[0] == 0x3F80u; }
__device__ __forceinline__ float loadraw(const void* p, size_t i, bool isbf){
    return isbf ? bf2f(((const u16*)p)[i]) : ((const float*)p)[i];
}
__device__ __forceinline__ void split3(float f, u16& h, u16& l, u16& q){
    h = f2bf(f); float r1 = f - bf2f(h);
    l = f2bf(r1); float r2 = r1 - bf2f(l);
    q = f2bf(r2);
}
__device__ __forceinline__ float gelu_f(float x){
    return 0.5f * x * (1.0f + tanhf(0.7978845608028654f * (x + 0.044715f * x * x * x)));
}
__device__ __forceinline__ f32x4 mfma16x16x32(s16x8 a, s16x8 b, f32x4 c){
    return __builtin_amdgcn_mfma_f32_16x16x32_bf16(a, b, c, 0, 0, 0);
}

__device__ __forceinline__ float blockReduce(float v, float* sb, bool domax){
    #pragma unroll
    for (int o = 32; o > 0; o >>= 1){
        float ov = __shfl_down(v, o, 64);
        v = domax ? fmaxf(v, ov) : (v + ov);
    }
    int w = threadIdx.x >> 6, lane = threadIdx.x & 63;
    if (lane == 0) sb[w] = v;
    __syncthreads();
    float r = domax ? fmaxf(fmaxf(sb[0], sb[1]), fmaxf(sb[2], sb[3]))
                    : (sb[0] + sb[1] + sb[2] + sb[3]);
    __syncthreads();
    return r;
}

// ---------- prep: 6 weight transposes + LN(x)+noop + coarse/sumexp init, 1 launch
struct TransDesc { const void* src; u16* dh; u16* dl; int K; int N; int start; int tilesX; };
struct TD6 { TransDesc d[6]; };

#define T_TRANS 3456
#define T_LNEND 4480   // 3456 + 1024
#define T_CIEND 4496   // + 16 coarse-init blocks
#define T_GRID  4497   // + 1 sumexp-zero block

__global__ __launch_bounds__(256) void prep_k(TD6 td,
        const void* x, const void* g, const void* bb, const void* nW, const void* nb,
        const void* cb3, const void* ginp,
        u16* __restrict__ xh, u16* __restrict__ xl, u16* __restrict__ xq,
        float* __restrict__ noop, float* __restrict__ coarse, float* __restrict__ sumexp){
    __shared__ float t[32][33];
    __shared__ float sb[4];
    bool isbf = probe_bf(ginp);
    int blk = blockIdx.x, tid = threadIdx.x;
    if (blk < T_TRANS){
        int e = 0;
        #pragma unroll
        for (int i = 1; i < 6; i++) if (blk >= td.d[i].start) e = i;
        TransDesc d = td.d[e];
        int rel = blk - d.start;
        int n0 = (rel % d.tilesX) * 32;
        int k0 = (rel / d.tilesX) * 32;
        int tx = tid & 31, ty = tid >> 5;
        #pragma unroll
        for (int i = 0; i < 32; i += 8)
            t[ty + i][tx] = loadraw(d.src, (size_t)(k0 + ty + i) * d.N + n0 + tx, isbf);
        __syncthreads();
        #pragma unroll
        for (int i = 0; i < 32; i += 8){
            float f = t[tx][ty + i];
            u16 h = f2bf(f);
            d.dh[(size_t)(n0 + ty + i) * d.K + k0 + tx] = h;
            if (d.dl)
                d.dl[(size_t)(n0 + ty + i) * d.K + k0 + tx] = f2bf(f - bf2f(h));
        }
    } else if (blk < T_LNEND){
        int b = blk - T_TRANS;
        float v[3];
        #pragma unroll
        for (int i = 0; i < 3; i++) v[i] = loadraw(x, (size_t)b * CB + tid + i * 256, isbf);
        float mean = blockReduce(v[0] + v[1] + v[2], sb, false) * (1.0f / 768.0f);
        float d0 = v[0] - mean, d1 = v[1] - mean, d2 = v[2] - mean;
        float var = blockReduce(d0*d0 + d1*d1 + d2*d2, sb, false) * (1.0f / 768.0f);
        float inv = 1.0f / sqrtf(var + 1e-5f);
        float dot = 0.0f;
        #pragma unroll
        for (int i = 0; i < 3; i++){
            int c = tid + i * 256;
            float xi = (v[i] - mean) * inv * loadraw(g, c, isbf) + loadraw(bb, c, isbf);
            u16 h, l, q; split3(xi, h, l, q);
            size_t o = (size_t)b * CB + c;
            xh[o] = h; xl[o] = l; xq[o] = q;
            dot += xi * loadraw(nW, c, isbf);
        }
        dot = blockReduce(dot, sb, false);
        if (tid == 0) noop[b] = dot + loadraw(nb, 0, isbf);
    } else if (blk < T_CIEND){
        int base = (blk - T_LNEND) * 16384;
        #pragma unroll
        for (int j = 0; j < 64; j++){
            int i = base + j * 256 + tid;
            coarse[i] = loadraw(cb3, i & 255, isbf);
        }
    } else {
        #pragma unroll
        for (int j = 0; j < 16; j++) sumexp[j * 256 + tid] = 0.0f;
    }
}

// ---------- GEMM TMxTN tile, 2x2 wave grid, register-prefetch pipeline, split-K via gridDim.z
// OUTMODE: 0=f32, 1=bf16, 2=split3 planes, 3=atomicAdd f32 (no bias/act),
//          4=f32 + per-row atomic sum of exp(val) into o1
template<int ASPLIT, int BSPLIT, int ACT, int OUTMODE, int TM, int TN>
__global__ __launch_bounds__(256) void gemm_k(
        const u16* __restrict__ Ah, const u16* __restrict__ Al, const u16* __restrict__ Aq,
        const u16* __restrict__ Bth, const u16* __restrict__ Btl,
        const void* __restrict__ bias, const void* __restrict__ ginp,
        void* __restrict__ o0, void* __restrict__ o1, void* __restrict__ o2,
        int M, int N, int K){
    constexpr int LDA = 40;           // 32 + 8 pad (bf16 elems)
    constexpr int MT = TM / 32;       // m-tiles per wave (wave grid 2x2)
    constexpr int NT = TN / 32;       // n-tiles per wave
    constexpr int APT = (TM == 128) ? 2 : 1;   // A prefetch regs per plane
    constexpr int BPT = (TN == 128) ? 2 : 1;
    __shared__ u16 As[ASPLIT][TM * LDA];
    __shared__ u16 Bs[BSPLIT][TN * LDA];
    bool isbf = probe_bf(ginp);
    const int m0 = blockIdx.y * TM, n0 = blockIdx.x * TN;
    const int tid = threadIdx.x;
    const int w = tid >> 6, lane = tid & 63, lm = lane & 15, q = lane >> 4;
    const int wr = w & 1, wc = w >> 1;
    const int kc = K / gridDim.z;
    const int kbeg = blockIdx.z * kc, kend = kbeg + kc;
    f32x4 acc[MT][NT];
    #pragma unroll
    for (int i = 0; i < MT; i++)
        #pragma unroll
        for (int j = 0; j < NT; j++) acc[i][j] = (f32x4)(0.0f);
    const int ar = (TM == 128) ? (tid >> 1) : (tid >> 2);
    const int ac = (TM == 128) ? ((tid & 1) * 16) : ((tid & 3) * 8);
    const int bn = (TN == 128) ? (tid >> 1) : (tid >> 2);
    const int bc = (TN == 128) ? ((tid & 1) * 16) : ((tid & 3) * 8);
    const u16* Apl[3] = { Ah, Al, Aq };
    const u16* Bpl[2] = { Bth, Btl };

    s16x8 pa[ASPLIT][APT], pb[BSPLIT][BPT];
    auto load_regs = [&](int kk){
        #pragma unroll
        for (int s = 0; s < ASPLIT; s++){
            const u16* sp = Apl[s] + (size_t)(m0 + ar) * K + kk + ac;
            pa[s][0] = *(const s16x8*)(sp);
            if (APT == 2) pa[s][1] = *(const s16x8*)(sp + 8);
        }
        #pragma unroll
        for (int s = 0; s < BSPLIT; s++){
            const u16* sp = Bpl[s] + (size_t)(n0 + bn) * K + kk + bc;
            pb[s][0] = *(const s16x8*)(sp);
            if (BPT == 2) pb[s][1] = *(const s16x8*)(sp + 8);
        }
    };

    load_regs(kbeg);
    for (int k0 = kbeg; k0 < kend; k0 += 32){
        __syncthreads();
        #pragma unroll
        for (int s = 0; s < ASPLIT; s++){
            *(s16x8*)&As[s][ar*LDA + ac] = pa[s][0];
            if (APT == 2) *(s16x8*)&As[s][ar*LDA + ac + 8] = pa[s][1];
        }
        #pragma unroll
        for (int s = 0; s < BSPLIT; s++){
            *(s16x8*)&Bs[s][bn*LDA + bc] = pb[s][0];
            if (BPT == 2) *(s16x8*)&Bs[s][bn*LDA + bc + 8] = pb[s][1];
        }
        __syncthreads();
        if (k0 + 32 < kend) load_regs(k0 + 32);   // in flight during compute

        s16x8 afr[ASPLIT][MT], bfr[BSPLIT][NT];
        #pragma unroll
        for (int mt = 0; mt < MT; mt++)
            #pragma unroll
            for (int s = 0; s < ASPLIT; s++)
                afr[s][mt] = *(const s16x8*)&As[s][((mt*2 + wr)*16 + lm)*LDA + q*8];
        #pragma unroll
        for (int nt = 0; nt < NT; nt++)
            #pragma unroll
            for (int s = 0; s < BSPLIT; s++)
                bfr[s][nt] = *(const s16x8*)&Bs[s][((nt*2 + wc)*16 + lm)*LDA + q*8];
        #pragma unroll
        for (int mt = 0; mt < MT; mt++)
            #pragma unroll
            for (int nt = 0; nt < NT; nt++){
                acc[mt][nt] = mfma16x16x32(afr[0][mt], bfr[0][nt], acc[mt][nt]);
                if (ASPLIT == 3){
                    acc[mt][nt] = mfma16x16x32(afr[1][mt], bfr[0][nt], acc[mt][nt]);
                    acc[mt][nt] = mfma16x16x32(afr[2][mt], bfr[0][nt], acc[mt][nt]);
                }
                if (BSPLIT == 2){
                    acc[mt][nt] = mfma16x16x32(afr[0][mt], bfr[1][nt], acc[mt][nt]);
                    if (ASPLIT == 3)
                        acc[mt][nt] = mfma16x16x32(afr[1][mt], bfr[1][nt], acc[mt][nt]);
                }
            }
    }

    if (OUTMODE == 3){
        #pragma unroll
        for (int nt = 0; nt < NT; nt++){
            int n = n0 + (nt*2 + wc)*16 + lm;
            #pragma unroll
            for (int mt = 0; mt < MT; mt++)
                #pragma unroll
                for (int r = 0; r < 4; r++){
                    int m = m0 + (mt*2 + wr)*16 + q*4 + r;
                    atomicAdd(&((float*)o0)[(size_t)m * N + n], acc[mt][nt][r]);
                }
        }
    } else if (OUTMODE == 4){
        #pragma unroll
        for (int mt = 0; mt < MT; mt++)
            #pragma unroll
            for (int r = 0; r < 4; r++){
                int m = m0 + (mt*2 + wr)*16 + q*4 + r;
                float esum = 0.0f;
                #pragma unroll
                for (int nt = 0; nt < NT; nt++){
                    int n = n0 + (nt*2 + wc)*16 + lm;
                    float vv = acc[mt][nt][r] + loadraw(bias, n, isbf);
                    ((float*)o0)[(size_t)m * N + n] = vv;
                    esum += expf(vv);
                }
                #pragma unroll
                for (int o = 8; o > 0; o >>= 1) esum += __shfl_down(esum, o, 16);
                if (lm == 0) atomicAdd(&((float*)o1)[m], esum);
            }
    } else {
        #pragma unroll
        for (int nt = 0; nt < NT; nt++){
            int n = n0 + (nt*2 + wc)*16 + lm;
            float bv = loadraw(bias, n, isbf);
            #pragma unroll
            for (int mt = 0; mt < MT; mt++){
                #pragma unroll
                for (int r = 0; r < 4; r++){
                    int m = m0 + (mt*2 + wr)*16 + q*4 + r;
                    float vv = acc[mt][nt][r] + bv;
                    if (ACT == 1) vv = gelu_f(vv);
                    size_t o = (size_t)m * N + n;
                    if (OUTMODE == 0)      ((float*)o0)[o] = vv;
                    else if (OUTMODE == 1) ((u16*)o0)[o] = f2bf(vv);
                    else {
                        u16 h, l, qq; split3(vv, h, l, qq);
                        ((u16*)o0)[o] = h; ((u16*)o1)[o] = l; ((u16*)o2)[o] = qq;
                    }
                }
            }
        }
    }
}

// ---------- fused top-4 + fine-input build: one block per (b, k)
// top-4 recomputed redundantly in the 4 blocks of b (deterministic -> consistent)
__global__ __launch_bounds__(256) void topkfine_k(const float* __restrict__ coarse,
        const void* __restrict__ emb, const void* __restrict__ ge, const void* __restrict__ be,
        const void* __restrict__ ginp, const u16* __restrict__ xh,
        u16* __restrict__ fin, unsigned char* __restrict__ ksel){
    __shared__ float sb[4];
    __shared__ float swv[4]; __shared__ int swi[4];
    __shared__ int sel4[4]; __shared__ int chosen_s;
    bool isbf = probe_bf(ginp);
    int bk = blockIdx.x, tid = threadIdx.x;
    int b = bk >> 2, kk = bk & 3;
    int w = tid >> 6, lane = tid & 63;
    float v = coarse[(size_t)b * NB + tid];
    if (kk == 0) ksel[(size_t)b * NB + tid] = (unsigned char)255;
    __syncthreads();
    for (int k = 0; k < 4; k++){
        float bv = v; int bi = tid;
        #pragma unroll
        for (int o = 32; o > 0; o >>= 1){
            float ov = __shfl_xor(bv, o, 64);
            int   oi = __shfl_xor(bi, o, 64);
            if (ov > bv || (ov == bv && oi < bi)){ bv = ov; bi = oi; }
        }
        if (lane == 0){ swv[w] = bv; swi[w] = bi; }
        __syncthreads();
        if (tid == 0){
            float cv = swv[0]; int ci = swi[0];
            #pragma unroll
            for (int j = 1; j < 4; j++)
                if (swv[j] > cv || (swv[j] == cv && swi[j] < ci)){ cv = swv[j]; ci = swi[j]; }
            sel4[k] = ci; chosen_s = ci;
        }
        __syncthreads();
        if (tid == chosen_s) v = -INFINITY;
    }
    if (kk == 0 && tid == 0){
        #pragma unroll
        for (int j = 0; j < 4; j++) ksel[(size_t)b * NB + sel4[j]] = (unsigned char)j;
    }
    int n = sel4[kk];
    float vv[3];
    #pragma unroll
    for (int i = 0; i < 3; i++) vv[i] = loadraw(emb, (size_t)n * CB + tid + i * 256, isbf);
    float mean = blockReduce(vv[0] + vv[1] + vv[2], sb, false) * (1.0f / 768.0f);
    float d0 = vv[0] - mean, d1 = vv[1] - mean, d2 = vv[2] - mean;
    float var = blockReduce(d0*d0 + d1*d1 + d2*d2, sb, false) * (1.0f / 768.0f);
    float inv = 1.0f / sqrtf(var + 1e-5f);
    u16* dst = fin + ((size_t)b * 4 + kk) * (2 * CB);
    #pragma unroll
    for (int i = 0; i < 3; i++){
        int c = tid + i * 256;
        dst[c] = xh[(size_t)b * CB + c];
        dst[CB + c] = f2bf((vv[i] - mean) * inv * loadraw(ge, c, isbf) + loadraw(be, c, isbf));
    }
}

// ---------- assemble flat output
__global__ __launch_bounds__(256) void out_k(const float* __restrict__ coarse,
        const float* __restrict__ fine, const float* __restrict__ sumexp,
        const unsigned char* __restrict__ ksel, const float* __restrict__ noop,
        const void* __restrict__ ginp, void* __restrict__ outp){
    u32 g0 = ((u32)blockIdx.x * 256u + (u32)threadIdx.x) * 8u;
    const u32 total = (u32)BATCH * (u32)OUTC;
    if (g0 >= total) return;
    bool isbf = probe_bf(ginp);
    float vals[8];
    #pragma unroll
    for (int e = 0; e < 8; e++){
        u32 gg = g0 + (u32)e;
        u32 qq = gg >> 17;                       // div by 131073 = 2^17 + 1
        int rr = (int)(gg & 131071u) - (int)qq;
        if (rr < 0){ qq -= 1u; rr += 131073; }
        int b = (int)qq;
        float val;
        if (rr == 0){
            val = noop[b];
        } else {
            int j = rr - 1;
            int ch = j >> 13;
            int rem = j & 8191;
            int fh = rem >> 9, cw = (rem >> 5) & 15, ff = rem & 31;
            int n = (ch << 4) + cw;
            val = coarse[(size_t)b * NB + n] - LOGF;
            int ks = ksel[(size_t)b * NB + n];
            if (ks != 255){
                int fr = b * 4 + ks;
                val += fine[((size_t)fr << 9) + (fh << 5) + ff] + (LOGF - logf(sumexp[fr]));
            }
        }
        vals[e] = val;
    }
    if (isbf){
        u16 res[8];
        #pragma unroll
        for (int e = 0; e < 8; e++) res[e] = f2bf(vals[e]);
        *(s16x8*)((u16*)outp + g0) = *(s16x8*)res;
    } else {
        float* of = (float*)outp + g0;
        *(float4*)(of)     = make_float4(vals[0], vals[1], vals[2], vals[3]);
        *(float4*)(of + 4) = make_float4(vals[4], vals[5], vals[6], vals[7]);
    }
}

extern "C" void kernel_launch(void* const* d_in, const int* in_sizes, int n_in,
                              void* d_out, int out_size, void* d_ws, size_t ws_size,
                              hipStream_t stream){
    (void)in_sizes; (void)n_in; (void)out_size; (void)ws_size;
    char* ws = (char*)d_ws;
    size_t off = 0;
    auto alloc = [&](size_t bytes){ void* p = ws + off; off += (bytes + 255) & ~(size_t)255; return p; };

    u16* xh  = (u16*)alloc((size_t)1024*768*2);
    u16* xl  = (u16*)alloc((size_t)1024*768*2);
    u16* xq  = (u16*)alloc((size_t)1024*768*2);
    u16* h1h = (u16*)alloc((size_t)1024*768*2);
    u16* h1l = (u16*)alloc((size_t)1024*768*2);
    u16* h1q = (u16*)alloc((size_t)1024*768*2);
    u16* h2h = (u16*)alloc((size_t)1024*768*2);
    u16* h2l = (u16*)alloc((size_t)1024*768*2);
    u16* h2q = (u16*)alloc((size_t)1024*768*2);
    float* coarse = (float*)alloc((size_t)1024*256*4);
    unsigned char* ksel = (unsigned char*)alloc((size_t)1024*256);
    float* noop   = (float*)alloc((size_t)1024*4);
    float* sumexp = (float*)alloc((size_t)4096*4);
    u16*   fin    = (u16*)  alloc((size_t)4096*1536*2);
    u16*   gg1    = (u16*)  alloc((size_t)4096*768*2);
    u16*   gg2    = (u16*)  alloc((size_t)4096*768*2);
    float* fine   = (float*)alloc((size_t)4096*512*4);
    u16* cW1th = (u16*)alloc((size_t)768*768*2);
    u16* cW1tl = (u16*)alloc((size_t)768*768*2);
    u16* cW2th = (u16*)alloc((size_t)768*768*2);
    u16* cW2tl = (u16*)alloc((size_t)768*768*2);
    u16* cW3th = (u16*)alloc((size_t)768*256*2);
    u16* cW3tl = (u16*)alloc((size_t)768*256*2);
    u16* fW1t  = (u16*)alloc((size_t)1536*768*2);
    u16* fW2t  = (u16*)alloc((size_t)768*768*2);
    u16* fW3t  = (u16*)alloc((size_t)768*512*2);

    const void* ginp = d_in[1];

    TD6 td;
    td.d[0] = { d_in[3],  cW1th, cW1tl,  768, 768,    0, 24 };  // 576 tiles
    td.d[1] = { d_in[5],  cW2th, cW2tl,  768, 768,  576, 24 };  // 576
    td.d[2] = { d_in[7],  cW3th, cW3tl,  768, 256, 1152,  8 };  // 192
    td.d[3] = { d_in[12], fW1t,  nullptr,1536, 768, 1344, 24 }; // 1152
    td.d[4] = { d_in[14], fW2t,  nullptr, 768, 768, 2496, 24 }; // 576
    td.d[5] = { d_in[16], fW3t,  nullptr, 768, 512, 3072, 16 }; // 384 -> 3456

    prep_k<<<T_GRID, 256, 0, stream>>>(td, d_in[0], d_in[1], d_in[2], d_in[18], d_in[19],
                                       d_in[8], ginp, xh, xl, xq, noop, coarse, sumexp);

    // coarse MLP: A split-3 x B split-2 (5 MFMA terms, near-fp32) for stable top-k; 64x64 tiles
    gemm_k<3,2,1,2,64,64><<<dim3(12, 16, 1), 256, 0, stream>>>(xh, xl, xq, cW1th, cW1tl,
            d_in[4], ginp, h1h, h1l, h1q, 1024, 768, 768);
    gemm_k<3,2,1,2,64,64><<<dim3(12, 16, 1), 256, 0, stream>>>(h1h, h1l, h1q, cW2th, cW2tl,
            d_in[6], ginp, h2h, h2l, h2q, 1024, 768, 768);
    // layer 3: split-K=3, atomic accumulate onto bias-initialized coarse
    gemm_k<3,2,0,3,64,64><<<dim3( 4, 16, 3), 256, 0, stream>>>(h2h, h2l, h2q, cW3th, cW3tl,
            nullptr, ginp, coarse, nullptr, nullptr, 1024, 256, 768);

    topkfine_k<<<4096, 256, 0, stream>>>(coarse, d_in[9], d_in[10], d_in[11], ginp, xh, fin, ksel);

    // fine MLP: plain bf16 MFMA, 128x128 tiles; layer 3 accumulates per-row sum(exp)
    gemm_k<1,1,1,1,128,128><<<dim3(6, 32, 1), 256, 0, stream>>>(fin, nullptr, nullptr, fW1t, nullptr,
            d_in[13], ginp, gg1, nullptr, nullptr, 4096, 768, 1536);
    gemm_k<1,1,1,1,128,128><<<dim3(6, 32, 1), 256, 0, stream>>>(gg1, nullptr, nullptr, fW2t, nullptr,
            d_in[15], ginp, gg2, nullptr, nullptr, 4096, 768, 768);
    gemm_k<1,1,0,4,128,64><<<dim3(8, 32, 1), 256, 0, stream>>>(gg2, nullptr, nullptr, fW3t, nullptr,
            d_in[17], ginp, fine, sumexp, nullptr, 4096, 512, 768);

    u32 total_chunks = ((u32)BATCH * (u32)OUTC) / 8u;
    u32 blocks = (total_chunks + 255u) / 256u;
    out_k<<<blocks, 256, 0, stream>>>(coarse, fine, sumexp, ksel, noop, ginp, d_out);
}

// Round 6
// 807.452 us; speedup vs baseline: 1.0825x; 1.0069x over previous
//
#include <hip/hip_runtime.h>
#include <hip/hip_bf16.h>
#include <math.h>

typedef unsigned short u16;
typedef unsigned int   u32;
typedef __attribute__((ext_vector_type(8))) short s16x8;
typedef __attribute__((ext_vector_type(4))) float f32x4;

#define CB 768
#define NB 256
#define FB 512
#define BATCH 1024
#define OUTC 131073
#define LOGF 6.2383246250395077f

__device__ __forceinline__ u16 f2bf(float f){
    u32 u = __float_as_uint(f);
    u32 r = u + 0x7FFFu + ((u >> 16) & 1u);
    return (u16)(r >> 16);
}
__device__ __forceinline__ float bf2f(u16 s){ return __uint_as_float(((u32)s) << 16); }
__device__ __forceinline__ bool probe_bf(const void* g){ return ((const u16*)g)[0] == 0x3F80u; }
__device__ __forceinline__ float loadraw(const void* p, size_t i, bool isbf){
    return isbf ? bf2f(((const u16*)p)[i]) : ((const float*)p)[i];
}
__device__ __forceinline__ void split3(float f, u16& h, u16& l, u16& q){
    h = f2bf(f); float r1 = f - bf2f(h);
    l = f2bf(r1); float r2 = r1 - bf2f(l);
    q = f2bf(r2);
}
__device__ __forceinline__ float gelu_f(float x){
    return 0.5f * x * (1.0f + tanhf(0.7978845608028654f * (x + 0.044715f * x * x * x)));
}
__device__ __forceinline__ f32x4 mfma16x16x32(s16x8 a, s16x8 b, f32x4 c){
    return __builtin_amdgcn_mfma_f32_16x16x32_bf16(a, b, c, 0, 0, 0);
}

__device__ __forceinline__ float blockReduce(float v, float* sb, bool domax){
    #pragma unroll
    for (int o = 32; o > 0; o >>= 1){
        float ov = __shfl_down(v, o, 64);
        v = domax ? fmaxf(v, ov) : (v + ov);
    }
    int w = threadIdx.x >> 6, lane = threadIdx.x & 63;
    if (lane == 0) sb[w] = v;
    __syncthreads();
    float r = domax ? fmaxf(fmaxf(sb[0], sb[1]), fmaxf(sb[2], sb[3]))
                    : (sb[0] + sb[1] + sb[2] + sb[3]);
    __syncthreads();
    return r;
}

// ---------- prep: transposes + LN(x)+noop + LN(emb) + coarse/ksel/sumexp init
struct TransDesc { const void* src; u16* dh; u16* dl; int K; int N; int start; int tilesX; };
struct TD6 { TransDesc d[6]; };

#define T_TRANS   3456
#define T_LNX_END 4480   // + 1024 LN(x) blocks
#define T_LEM_END 4736   // + 256 LN(emb) blocks
#define T_CI_END  4752   // + 16 coarse-bias-init blocks
#define T_KS_END  4768   // + 16 ksel-init blocks
#define T_GRID    4769   // + 1 sumexp-zero block

__global__ __launch_bounds__(256) void prep_k(TD6 td,
        const void* x, const void* g, const void* bb, const void* nW, const void* nb,
        const void* emb, const void* ge, const void* be, const void* cb3, const void* ginp,
        u16* __restrict__ xh, u16* __restrict__ xl, u16* __restrict__ xq,
        u16* __restrict__ lnemb, float* __restrict__ noop,
        float* __restrict__ coarse, unsigned char* __restrict__ ksel,
        float* __restrict__ sumexp){
    __shared__ float t[32][33];
    __shared__ float sb[4];
    bool isbf = probe_bf(ginp);
    int blk = blockIdx.x, tid = threadIdx.x;
    if (blk < T_TRANS){
        int e = 0;
        #pragma unroll
        for (int i = 1; i < 6; i++) if (blk >= td.d[i].start) e = i;
        TransDesc d = td.d[e];
        int rel = blk - d.start;
        int n0 = (rel % d.tilesX) * 32;
        int k0 = (rel / d.tilesX) * 32;
        int tx = tid & 31, ty = tid >> 5;
        #pragma unroll
        for (int i = 0; i < 32; i += 8)
            t[ty + i][tx] = loadraw(d.src, (size_t)(k0 + ty + i) * d.N + n0 + tx, isbf);
        __syncthreads();
        #pragma unroll
        for (int i = 0; i < 32; i += 8){
            float f = t[tx][ty + i];
            u16 h = f2bf(f);
            d.dh[(size_t)(n0 + ty + i) * d.K + k0 + tx] = h;
            if (d.dl)
                d.dl[(size_t)(n0 + ty + i) * d.K + k0 + tx] = f2bf(f - bf2f(h));
        }
    } else if (blk < T_LNX_END){
        int b = blk - T_TRANS;
        float v[3];
        #pragma unroll
        for (int i = 0; i < 3; i++) v[i] = loadraw(x, (size_t)b * CB + tid + i * 256, isbf);
        float mean = blockReduce(v[0] + v[1] + v[2], sb, false) * (1.0f / 768.0f);
        float d0 = v[0] - mean, d1 = v[1] - mean, d2 = v[2] - mean;
        float var = blockReduce(d0*d0 + d1*d1 + d2*d2, sb, false) * (1.0f / 768.0f);
        float inv = 1.0f / sqrtf(var + 1e-5f);
        float dot = 0.0f;
        #pragma unroll
        for (int i = 0; i < 3; i++){
            int c = tid + i * 256;
            float xi = (v[i] - mean) * inv * loadraw(g, c, isbf) + loadraw(bb, c, isbf);
            u16 h, l, q; split3(xi, h, l, q);
            size_t o = (size_t)b * CB + c;
            xh[o] = h; xl[o] = l; xq[o] = q;
            dot += xi * loadraw(nW, c, isbf);
        }
        dot = blockReduce(dot, sb, false);
        if (tid == 0) noop[b] = dot + loadraw(nb, 0, isbf);
    } else if (blk < T_LEM_END){
        int n = blk - T_LNX_END;       // LN(emb[n]) once per n (shared by all b)
        float v[3];
        #pragma unroll
        for (int i = 0; i < 3; i++) v[i] = loadraw(emb, (size_t)n * CB + tid + i * 256, isbf);
        float mean = blockReduce(v[0] + v[1] + v[2], sb, false) * (1.0f / 768.0f);
        float d0 = v[0] - mean, d1 = v[1] - mean, d2 = v[2] - mean;
        float var = blockReduce(d0*d0 + d1*d1 + d2*d2, sb, false) * (1.0f / 768.0f);
        float inv = 1.0f / sqrtf(var + 1e-5f);
        #pragma unroll
        for (int i = 0; i < 3; i++){
            int c = tid + i * 256;
            lnemb[(size_t)n * CB + c] =
                f2bf((v[i] - mean) * inv * loadraw(ge, c, isbf) + loadraw(be, c, isbf));
        }
    } else if (blk < T_CI_END){
        int base = (blk - T_LEM_END) * 16384;
        #pragma unroll
        for (int j = 0; j < 64; j++){
            int i = base + j * 256 + tid;
            coarse[i] = loadraw(cb3, i & 255, isbf);
        }
    } else if (blk < T_KS_END){
        int base = (blk - T_CI_END) * 4096;
        u32* kp = (u32*)ksel;
        #pragma unroll
        for (int j = 0; j < 16; j++) kp[base + j * 256 + tid] = 0xFFFFFFFFu;
    } else {
        #pragma unroll
        for (int j = 0; j < 16; j++) sumexp[j * 256 + tid] = 0.0f;
    }
}

// ---------- GEMM TMxTN tile, 2x2 wave grid, register-prefetch pipeline, split-K via gridDim.z
// GATHER: A row index = gidx[m0+ar] into Ah (used for lnemb gather)
// OUTMODE: 0=f32 (bias may be null), 1=bf16, 2=split3 planes, 3=atomicAdd f32,
//          4=f32 + per-row atomic sum of exp into o1, 5=bf16 gelu(acc+bias+xaux[m>>2][n]) (xaux=o1)
template<int ASPLIT, int BSPLIT, int ACT, int OUTMODE, int TM, int TN, int GATHER>
__global__ __launch_bounds__(256) void gemm_k(
        const u16* __restrict__ Ah, const u16* __restrict__ Al, const u16* __restrict__ Aq,
        const int* __restrict__ gidx,
        const u16* __restrict__ Bth, const u16* __restrict__ Btl,
        const void* __restrict__ bias, const void* __restrict__ ginp,
        void* __restrict__ o0, void* __restrict__ o1, void* __restrict__ o2,
        int M, int N, int K, int lda, int ldb){
    constexpr int LDA = 40;
    constexpr int MT = TM / 32;
    constexpr int NT = TN / 32;
    constexpr int APT = (TM == 128) ? 2 : 1;
    constexpr int BPT = (TN == 128) ? 2 : 1;
    __shared__ u16 As[ASPLIT][TM * LDA];
    __shared__ u16 Bs[BSPLIT][TN * LDA];
    bool isbf = probe_bf(ginp);
    const int m0 = blockIdx.y * TM, n0 = blockIdx.x * TN;
    const int tid = threadIdx.x;
    const int w = tid >> 6, lane = tid & 63, lm = lane & 15, q = lane >> 4;
    const int wr = w & 1, wc = w >> 1;
    const int kc = K / gridDim.z;
    const int kbeg = blockIdx.z * kc, kend = kbeg + kc;
    f32x4 acc[MT][NT];
    #pragma unroll
    for (int i = 0; i < MT; i++)
        #pragma unroll
        for (int j = 0; j < NT; j++) acc[i][j] = (f32x4)(0.0f);
    const int ar = (TM == 128) ? (tid >> 1) : (tid >> 2);
    const int ac = (TM == 128) ? ((tid & 1) * 16) : ((tid & 3) * 8);
    const int bn = (TN == 128) ? (tid >> 1) : (tid >> 2);
    const int bc = (TN == 128) ? ((tid & 1) * 16) : ((tid & 3) * 8);
    const u16* Apl[3] = { Ah, Al, Aq };
    const u16* Bpl[2] = { Bth, Btl };
    const int arow = GATHER ? gidx[m0 + ar] : (m0 + ar);

    s16x8 pa[ASPLIT][APT], pb[BSPLIT][BPT];
    auto load_regs = [&](int kk){
        #pragma unroll
        for (int s = 0; s < ASPLIT; s++){
            const u16* sp = Apl[s] + (size_t)arow * lda + kk + ac;
            pa[s][0] = *(const s16x8*)(sp);
            if (APT == 2) pa[s][1] = *(const s16x8*)(sp + 8);
        }
        #pragma unroll
        for (int s = 0; s < BSPLIT; s++){
            const u16* sp = Bpl[s] + (size_t)(n0 + bn) * ldb + kk + bc;
            pb[s][0] = *(const s16x8*)(sp);
            if (BPT == 2) pb[s][1] = *(const s16x8*)(sp + 8);
        }
    };

    load_regs(kbeg);
    for (int k0 = kbeg; k0 < kend; k0 += 32){
        __syncthreads();
        #pragma unroll
        for (int s = 0; s < ASPLIT; s++){
            *(s16x8*)&As[s][ar*LDA + ac] = pa[s][0];
            if (APT == 2) *(s16x8*)&As[s][ar*LDA + ac + 8] = pa[s][1];
        }
        #pragma unroll
        for (int s = 0; s < BSPLIT; s++){
            *(s16x8*)&Bs[s][bn*LDA + bc] = pb[s][0];
            if (BPT == 2) *(s16x8*)&Bs[s][bn*LDA + bc + 8] = pb[s][1];
        }
        __syncthreads();
        if (k0 + 32 < kend) load_regs(k0 + 32);

        s16x8 afr[ASPLIT][MT], bfr[BSPLIT][NT];
        #pragma unroll
        for (int mt = 0; mt < MT; mt++)
            #pragma unroll
            for (int s = 0; s < ASPLIT; s++)
                afr[s][mt] = *(const s16x8*)&As[s][((mt*2 + wr)*16 + lm)*LDA + q*8];
        #pragma unroll
        for (int nt = 0; nt < NT; nt++)
            #pragma unroll
            for (int s = 0; s < BSPLIT; s++)
                bfr[s][nt] = *(const s16x8*)&Bs[s][((nt*2 + wc)*16 + lm)*LDA + q*8];
        #pragma unroll
        for (int mt = 0; mt < MT; mt++)
            #pragma unroll
            for (int nt = 0; nt < NT; nt++){
                acc[mt][nt] = mfma16x16x32(afr[0][mt], bfr[0][nt], acc[mt][nt]);
                if (ASPLIT == 3){
                    acc[mt][nt] = mfma16x16x32(afr[1][mt], bfr[0][nt], acc[mt][nt]);
                    acc[mt][nt] = mfma16x16x32(afr[2][mt], bfr[0][nt], acc[mt][nt]);
                }
                if (BSPLIT == 2){
                    acc[mt][nt] = mfma16x16x32(afr[0][mt], bfr[1][nt], acc[mt][nt]);
                    if (ASPLIT == 3)
                        acc[mt][nt] = mfma16x16x32(afr[1][mt], bfr[1][nt], acc[mt][nt]);
                }
            }
    }

    if (OUTMODE == 3){
        #pragma unroll
        for (int nt = 0; nt < NT; nt++){
            int n = n0 + (nt*2 + wc)*16 + lm;
            #pragma unroll
            for (int mt = 0; mt < MT; mt++)
                #pragma unroll
                for (int r = 0; r < 4; r++){
                    int m = m0 + (mt*2 + wr)*16 + q*4 + r;
                    atomicAdd(&((float*)o0)[(size_t)m * N + n], acc[mt][nt][r]);
                }
        }
    } else if (OUTMODE == 4){
        #pragma unroll
        for (int mt = 0; mt < MT; mt++)
            #pragma unroll
            for (int r = 0; r < 4; r++){
                int m = m0 + (mt*2 + wr)*16 + q*4 + r;
                float esum = 0.0f;
                #pragma unroll
                for (int nt = 0; nt < NT; nt++){
                    int n = n0 + (nt*2 + wc)*16 + lm;
                    float vv = acc[mt][nt][r] + (bias ? loadraw(bias, n, isbf) : 0.0f);
                    ((float*)o0)[(size_t)m * N + n] = vv;
                    esum += expf(vv);
                }
                #pragma unroll
                for (int o = 8; o > 0; o >>= 1) esum += __shfl_down(esum, o, 16);
                if (lm == 0) atomicAdd(&((float*)o1)[m], esum);
            }
    } else if (OUTMODE == 5){
        #pragma unroll
        for (int nt = 0; nt < NT; nt++){
            int n = n0 + (nt*2 + wc)*16 + lm;
            float bv = bias ? loadraw(bias, n, isbf) : 0.0f;
            #pragma unroll
            for (int mt = 0; mt < MT; mt++){
                #pragma unroll
                for (int r = 0; r < 4; r++){
                    int m = m0 + (mt*2 + wr)*16 + q*4 + r;
                    float xv = ((const float*)o1)[(size_t)(m >> 2) * N + n];
                    ((u16*)o0)[(size_t)m * N + n] = f2bf(gelu_f(acc[mt][nt][r] + bv + xv));
                }
            }
        }
    } else {
        #pragma unroll
        for (int nt = 0; nt < NT; nt++){
            int n = n0 + (nt*2 + wc)*16 + lm;
            float bv = bias ? loadraw(bias, n, isbf) : 0.0f;
            #pragma unroll
            for (int mt = 0; mt < MT; mt++){
                #pragma unroll
                for (int r = 0; r < 4; r++){
                    int m = m0 + (mt*2 + wr)*16 + q*4 + r;
                    float vv = acc[mt][nt][r] + bv;
                    if (ACT == 1) vv = gelu_f(vv);
                    size_t o = (size_t)m * N + n;
                    if (OUTMODE == 0)      ((float*)o0)[o] = vv;
                    else if (OUTMODE == 1) ((u16*)o0)[o] = f2bf(vv);
                    else {
                        u16 h, l, qq; split3(vv, h, l, qq);
                        ((u16*)o0)[o] = h; ((u16*)o1)[o] = l; ((u16*)o2)[o] = qq;
                    }
                }
            }
        }
    }
}

// ---------- per-row top-4: one wave per batch row (ties -> smaller index)
__global__ __launch_bounds__(256) void topk_k(const float* __restrict__ coarse,
        int* __restrict__ idx, unsigned char* __restrict__ ksel){
    int w = threadIdx.x >> 6, lane = threadIdx.x & 63;
    int b = blockIdx.x * 4 + w;
    const float* cr = coarse + (size_t)b * NB;
    float v[4]; int id[4];
    #pragma unroll
    for (int j = 0; j < 4; j++){ id[j] = lane + 64*j; v[j] = cr[id[j]]; }
    for (int k = 0; k < 4; k++){
        float bv = v[0]; int bi = id[0];
        #pragma unroll
        for (int j = 1; j < 4; j++)
            if (v[j] > bv || (v[j] == bv && id[j] < bi)){ bv = v[j]; bi = id[j]; }
        #pragma unroll
        for (int o = 32; o > 0; o >>= 1){
            float ov = __shfl_xor(bv, o, 64);
            int   oi = __shfl_xor(bi, o, 64);
            if (ov > bv || (ov == bv && oi < bi)){ bv = ov; bi = oi; }
        }
        if (lane == 0){ idx[b*4 + k] = bi; ksel[(size_t)b * NB + bi] = (unsigned char)k; }
        #pragma unroll
        for (int j = 0; j < 4; j++) if (id[j] == bi) v[j] = -INFINITY;
    }
}

// ---------- assemble flat output
__global__ __launch_bounds__(256) void out_k(const float* __restrict__ coarse,
        const float* __restrict__ fine, const float* __restrict__ sumexp,
        const unsigned char* __restrict__ ksel, const float* __restrict__ noop,
        const void* __restrict__ ginp, void* __restrict__ outp){
    u32 g0 = ((u32)blockIdx.x * 256u + (u32)threadIdx.x) * 8u;
    const u32 total = (u32)BATCH * (u32)OUTC;
    if (g0 >= total) return;
    bool isbf = probe_bf(ginp);
    float vals[8];
    #pragma unroll
    for (int e = 0; e < 8; e++){
        u32 gg = g0 + (u32)e;
        u32 qq = gg >> 17;                       // div by 131073 = 2^17 + 1
        int rr = (int)(gg & 131071u) - (int)qq;
        if (rr < 0){ qq -= 1u; rr += 131073; }
        int b = (int)qq;
        float val;
        if (rr == 0){
            val = noop[b];
        } else {
            int j = rr - 1;
            int ch = j >> 13;
            int rem = j & 8191;
            int fh = rem >> 9, cw = (rem >> 5) & 15, ff = rem & 31;
            int n = (ch << 4) + cw;
            val = coarse[(size_t)b * NB + n] - LOGF;
            int ks = ksel[(size_t)b * NB + n];
            if (ks != 255){
                int fr = b * 4 + ks;
                val += fine[((size_t)fr << 9) + (fh << 5) + ff] + (LOGF - logf(sumexp[fr]));
            }
        }
        vals[e] = val;
    }
    if (isbf){
        u16 res[8];
        #pragma unroll
        for (int e = 0; e < 8; e++) res[e] = f2bf(vals[e]);
        *(s16x8*)((u16*)outp + g0) = *(s16x8*)res;
    } else {
        float* of = (float*)outp + g0;
        *(float4*)(of)     = make_float4(vals[0], vals[1], vals[2], vals[3]);
        *(float4*)(of + 4) = make_float4(vals[4], vals[5], vals[6], vals[7]);
    }
}

extern "C" void kernel_launch(void* const* d_in, const int* in_sizes, int n_in,
                              void* d_out, int out_size, void* d_ws, size_t ws_size,
                              hipStream_t stream){
    (void)in_sizes; (void)n_in; (void)out_size; (void)ws_size;
    char* ws = (char*)d_ws;
    size_t off = 0;
    auto alloc = [&](size_t bytes){ void* p = ws + off; off += (bytes + 255) & ~(size_t)255; return p; };

    u16* xh  = (u16*)alloc((size_t)1024*768*2);
    u16* xl  = (u16*)alloc((size_t)1024*768*2);
    u16* xq  = (u16*)alloc((size_t)1024*768*2);
    u16* h1h = (u16*)alloc((size_t)1024*768*2);
    u16* h1l = (u16*)alloc((size_t)1024*768*2);
    u16* h1q = (u16*)alloc((size_t)1024*768*2);
    u16* h2h = (u16*)alloc((size_t)1024*768*2);
    u16* h2l = (u16*)alloc((size_t)1024*768*2);
    u16* h2q = (u16*)alloc((size_t)1024*768*2);
    u16* lnemb = (u16*)alloc((size_t)256*768*2);
    float* coarse = (float*)alloc((size_t)1024*256*4);
    unsigned char* ksel = (unsigned char*)alloc((size_t)1024*256);
    float* noop   = (float*)alloc((size_t)1024*4);
    float* sumexp = (float*)alloc((size_t)4096*4);
    int*   idx    = (int*)alloc((size_t)4096*4);
    float* xpart  = (float*)alloc((size_t)1024*768*4);
    u16*   gg1    = (u16*)  alloc((size_t)4096*768*2);
    u16*   gg2    = (u16*)  alloc((size_t)4096*768*2);
    float* fine   = (float*)alloc((size_t)4096*512*4);
    u16* cW1th = (u16*)alloc((size_t)768*768*2);
    u16* cW1tl = (u16*)alloc((size_t)768*768*2);
    u16* cW2th = (u16*)alloc((size_t)768*768*2);
    u16* cW2tl = (u16*)alloc((size_t)768*768*2);
    u16* cW3th = (u16*)alloc((size_t)768*256*2);
    u16* cW3tl = (u16*)alloc((size_t)768*256*2);
    u16* fW1t  = (u16*)alloc((size_t)768*1536*2);
    u16* fW2t  = (u16*)alloc((size_t)768*768*2);
    u16* fW3t  = (u16*)alloc((size_t)512*768*2);

    const void* ginp = d_in[1];

    TD6 td;
    td.d[0] = { d_in[3],  cW1th, cW1tl,  768, 768,    0, 24 };  // 576 tiles
    td.d[1] = { d_in[5],  cW2th, cW2tl,  768, 768,  576, 24 };  // 576
    td.d[2] = { d_in[7],  cW3th, cW3tl,  768, 256, 1152,  8 };  // 192
    td.d[3] = { d_in[12], fW1t,  nullptr,1536, 768, 1344, 24 }; // 1152
    td.d[4] = { d_in[14], fW2t,  nullptr, 768, 768, 2496, 24 }; // 576
    td.d[5] = { d_in[16], fW3t,  nullptr, 768, 512, 3072, 16 }; // 384 -> 3456

    prep_k<<<T_GRID, 256, 0, stream>>>(td, d_in[0], d_in[1], d_in[2], d_in[18], d_in[19],
            d_in[9], d_in[10], d_in[11], d_in[8], ginp,
            xh, xl, xq, lnemb, noop, coarse, ksel, sumexp);

    // xpart = xn @ fW1[:768]  (shared across the K=4 routed rows of each b)
    gemm_k<1,1,0,0,128,128,0><<<dim3(6, 8, 1), 256, 0, stream>>>(
            xh, nullptr, nullptr, nullptr, fW1t, nullptr,
            nullptr, ginp, xpart, nullptr, nullptr, 1024, 768, 768, 768, 1536);

    // coarse MLP: A split-3 x B split-2 (5 MFMA terms, near-fp32) for stable top-k
    gemm_k<3,2,1,2,64,64,0><<<dim3(12, 16, 1), 256, 0, stream>>>(
            xh, xl, xq, nullptr, cW1th, cW1tl,
            d_in[4], ginp, h1h, h1l, h1q, 1024, 768, 768, 768, 768);
    gemm_k<3,2,1,2,64,64,0><<<dim3(12, 16, 1), 256, 0, stream>>>(
            h1h, h1l, h1q, nullptr, cW2th, cW2tl,
            d_in[6], ginp, h2h, h2l, h2q, 1024, 768, 768, 768, 768);
    gemm_k<3,2,0,3,64,64,0><<<dim3( 4, 16, 3), 256, 0, stream>>>(
            h2h, h2l, h2q, nullptr, cW3th, cW3tl,
            nullptr, ginp, coarse, nullptr, nullptr, 1024, 256, 768, 768, 768);

    topk_k<<<256, 256, 0, stream>>>(coarse, idx, ksel);

    // fine layer 1: epart = lnemb[idx] @ fW1[768:]; out = gelu(epart + xpart + fb1)
    gemm_k<1,1,0,5,128,128,1><<<dim3(6, 32, 1), 256, 0, stream>>>(
            lnemb, nullptr, nullptr, idx, fW1t + 768, nullptr,
            d_in[13], ginp, gg1, xpart, nullptr, 4096, 768, 768, 768, 1536);
    gemm_k<1,1,1,1,128,128,0><<<dim3(6, 32, 1), 256, 0, stream>>>(
            gg1, nullptr, nullptr, nullptr, fW2t, nullptr,
            d_in[15], ginp, gg2, nullptr, nullptr, 4096, 768, 768, 768, 768);
    gemm_k<1,1,0,4,128,128,0><<<dim3(4, 32, 1), 256, 0, stream>>>(
            gg2, nullptr, nullptr, nullptr, fW3t, nullptr,
            d_in[17], ginp, fine, sumexp, nullptr, 4096, 512, 768, 768, 768);

    u32 total_chunks = ((u32)BATCH * (u32)OUTC) / 8u;
    u32 blocks = (total_chunks + 255u) / 256u;
    out_k<<<blocks, 256, 0, stream>>>(coarse, fine, sumexp, ksel, noop, ginp, d_out);
}